// Round 11
// baseline (76.226 us; speedup 1.0000x reference)
//
#include <hip/hip_runtime.h>
#include <hip/hip_bf16.h>

#define NN 100000
#define DEG 16
#define NF 128
#define HID 128
#define NC 16
#define NB 10000

#define AS1 __attribute__((address_space(1)))
#define AS3 __attribute__((address_space(3)))

typedef float f32x16 __attribute__((ext_vector_type(16)));
typedef short s16x8 __attribute__((ext_vector_type(8)));

__device__ __forceinline__ ushort f2bf(float f) {   // RNE (prep kernel only)
    unsigned u = __builtin_bit_cast(unsigned, f);
    return (ushort)((u + 0x7FFFu + ((u >> 16) & 1u)) >> 16);
}
__device__ __forceinline__ float bf2f(ushort h) {
    return __builtin_bit_cast(float, (unsigned)h << 16);
}
// HW packed fp32->bf16 RNE: dst = {lo: cvt(a), hi: cvt(b)}
__device__ __forceinline__ uint cvtpk(float a, float b) {
    uint r;
    asm("v_cvt_pk_bf16_f32 %0, %1, %2" : "=v"(r) : "v"(a), "v"(b));
    return r;
}
__device__ __forceinline__ s16x8 pack8(float4 a, float4 b) {
    uint4 u;
    u.x = cvtpk(a.x, a.y);
    u.y = cvtpk(a.z, a.w);
    u.z = cvtpk(b.x, b.y);
    u.w = cvtpk(b.z, b.w);
    return __builtin_bit_cast(s16x8, u);
}
// XOR swizzle within a 256B LDS row: 16 slots of 16B (T2, conflict-free b128)
__device__ __forceinline__ int swz16(int row, int bo) {
    return row * 256 + (bo ^ ((row & 15) << 4));
}
// XOR swizzle for the 512B fp32 A-rows in gemm1 (32 slots of 16B)
__device__ __forceinline__ uint swzA(uint row, uint bo) {
    return bo ^ ((row & 31u) << 4);
}
// pi: storage position p -> true feature index j (within 128)
__device__ __forceinline__ int pi_feat(int p) {
    const int n = p >> 5, h = (p >> 4) & 1, g = p & 15;
    return 32 * n + 4 * h + (g & 3) + 8 * (g >> 2);
}

// ---------------------------------------------------------------------------
// Prep: W1 -> bf16 MFMA A-fragments WFh; W2 -> WF2 with pi-permuted k.
// ---------------------------------------------------------------------------
__global__ __launch_bounds__(256)
void wf_prep(const float* __restrict__ W1, const float* __restrict__ W2,
             ushort* __restrict__ WFh, ushort* __restrict__ WF2) {
    const int t = blockIdx.x * 256 + threadIdx.x;
    if (t >= 72 * 64) return;
    const int frag = t >> 6;
    const int lane = t & 63;
    const int k0 = (frag & 7) * 16 + (lane >> 5) * 8;

    if (frag < 64) {
        const int vcol = (frag >> 3) * 32 + (lane & 31);
        const float* src = (vcol < 128) ? W1 + (size_t)vcol * 256
                                        : W1 + (size_t)(vcol - 128) * 256 + 128;
        ushort hh[8];
        #pragma unroll
        for (int j = 0; j < 8; ++j) hh[j] = f2bf(src[k0 + j]);
        *(uint4*)(WFh + (size_t)t * 8) = *(const uint4*)hh;
    } else {
        const int vcol = lane & 31;
        const float* src = (vcol < 16) ? W2 + (size_t)vcol * 256
                                       : W2 + (size_t)(vcol - 16) * 256 + 128;
        ushort hh[8];
        #pragma unroll
        for (int j = 0; j < 8; ++j) hh[j] = f2bf(src[pi_feat(k0 + j)]);
        *(uint4*)(WF2 + (size_t)((frag - 64) * 64 + lane) * 8) = *(const uint4*)hh;
    }
}

// ---------------------------------------------------------------------------
// GEMM1 (LDS-staged A, LDS-transposed epilogue): 256 threads, 64 nodes x 256.
// Stage: contiguous 32KB X tile -> LDS (source pre-swizzled, rule #21).
// Compute: swapped-operand MFMA -> lane owns one node (pi-ordered feats).
// Epilogue: acc -> LDS (XOR-swizzled ds_write) -> barrier -> DENSE stores:
//   16 threads cover one full 256B Qb row (wave = 1KB contiguous), 8 threads
//   one 128B Pf row. Kills the 64-lines-per-store-instr L2 transaction storm.
// ---------------------------------------------------------------------------
__global__ __launch_bounds__(256, 3)
void gemm1(const float* __restrict__ X, const ushort* __restrict__ WFh,
           ushort* __restrict__ Qb, unsigned char* __restrict__ Pf) {
    __shared__ char As[64 * 512];   // 32KB: stage X; reused as Qs(16K)+Ps(8K)
    const int t = threadIdx.x;
    const int lane = t & 63;
    const int w = t >> 6;          // 0..3
    const int row0 = blockIdx.x * 64;

    // ---- stage: 32 chunks of 1KB; wave w takes chunks w, w+4, ... (8 issues)
    #pragma unroll
    for (int j = 0; j < 8; ++j) {
        const uint chunk = (uint)(j * 4 + w);
        const uint o = chunk * 1024u + (uint)lane * 16u;
        const uint rrow = o >> 9;
        const uint bo = o & 511u;
        int grow = row0 + (int)rrow;
        if (grow > NN - 1) grow = NN - 1;
        const char* src = (const char*)X + (size_t)grow * 512 + swzA(rrow, bo);
        __builtin_amdgcn_global_load_lds((const AS1 void*)src,
                                         (AS3 void*)(As + chunk * 1024), 16, 0, 0);
    }
    __syncthreads();

    const int wm = w & 1;          // node frag
    const int wn = w >> 1;         // feature half
    const uint arow = (uint)(wm * 32 + (lane & 31));
    const char* abase = As + arow * 512;

    f32x16 acc[4];
    #pragma unroll
    for (int n = 0; n < 4; ++n)
        acc[n] = (f32x16){0,0,0,0,0,0,0,0,0,0,0,0,0,0,0,0};

    #pragma unroll
    for (int kk = 0; kk < 8; ++kk) {
        const uint bo = (uint)(kk * 64 + (lane >> 5) * 32);
        const float4 fa = *(const float4*)(abase + swzA(arow, bo));
        const float4 fb = *(const float4*)(abase + swzA(arow, bo + 16));
        const s16x8 a = pack8(fa, fb);
        #pragma unroll
        for (int n = 0; n < 4; ++n) {
            const int cf = wn * 4 + n;
            const s16x8 b = *(const s16x8*)(WFh + (size_t)((cf * 8 + kk) * 64 + lane) * 8);
            acc[n] = __builtin_amdgcn_mfma_f32_32x32x16_bf16(b, a, acc[n], 0, 0, 0);
        }
    }
    __syncthreads();   // all ds_reads of As done before re-use

    // ---- acc -> LDS (swizzled), per-lane chunks
    char* Qs = As;            // [64 rows][256B] bf16, pi-ordered
    char* Ps = As + 16384;    // [64 rows][128B] fp8,  pi-ordered
    const int nloc = wm * 32 + (lane & 31);
    const int h = lane >> 5;
    if (wn == 0) {
        #pragma unroll
        for (int n = 0; n < 4; ++n) {
            uint4 u0, u1;
            u0.x = cvtpk(acc[n][0], acc[n][1]);
            u0.y = cvtpk(acc[n][2], acc[n][3]);
            u0.z = cvtpk(acc[n][4], acc[n][5]);
            u0.w = cvtpk(acc[n][6], acc[n][7]);
            u1.x = cvtpk(acc[n][8], acc[n][9]);
            u1.y = cvtpk(acc[n][10], acc[n][11]);
            u1.z = cvtpk(acc[n][12], acc[n][13]);
            u1.w = cvtpk(acc[n][14], acc[n][15]);
            const int bo = n * 64 + h * 32;
            *(uint4*)(Qs + nloc * 256 + (bo ^ ((nloc & 15) << 4))) = u0;
            *(uint4*)(Qs + nloc * 256 + ((bo + 16) ^ ((nloc & 15) << 4))) = u1;
        }
    } else {
        #pragma unroll
        for (int n = 0; n < 4; ++n) {
            uint uu[4];
            #pragma unroll
            for (int q = 0; q < 4; ++q) {
                int v = __builtin_amdgcn_cvt_pk_fp8_f32(
                    acc[n][4 * q], acc[n][4 * q + 1], 0, false);
                v = __builtin_amdgcn_cvt_pk_fp8_f32(
                    acc[n][4 * q + 2], acc[n][4 * q + 3], v, true);
                uu[q] = (uint)v;
            }
            const int bo = n * 32 + h * 16;
            *(uint4*)(Ps + nloc * 128 + (bo ^ ((nloc & 7) << 4))) = *(const uint4*)uu;
        }
    }
    __syncthreads();

    // ---- dense stores: Q rows (256B, 16 thr/row), P rows (128B, 8 thr/row)
    {
        const int s = t & 15, rbase = t >> 4;   // 16 rows per pass
        #pragma unroll
        for (int p = 0; p < 4; ++p) {
            const int r = rbase + p * 16;
            const int grow = row0 + r;
            const uint4 v = *(const uint4*)(Qs + r * 256 + ((s * 16) ^ ((r & 15) << 4)));
            if (grow < NN)
                *(uint4*)((char*)Qb + (size_t)grow * 256 + s * 16) = v;
        }
    }
    {
        const int s = t & 7, rbase = t >> 3;    // 32 rows per pass
        #pragma unroll
        for (int p = 0; p < 2; ++p) {
            const int r = rbase + p * 32;
            const int grow = row0 + r;
            const uint4 v = *(const uint4*)(Ps + r * 128 + ((s * 16) ^ ((r & 7) << 4)));
            if (grow < NN)
                *(uint4*)((char*)Pf + (size_t)grow * 128 + s * 16) = v;
        }
    }
}

// ---------------------------------------------------------------------------
// Fused aggregate + GEMM2 (all pi-ordered; elementwise ops order-agnostic).
// Block = 128 nodes, 32KB LDS.
// Phase A: h1[n] = relu(Qb[n] + mean_d Pf[nbr(n,d)]) -> swizzled LDS (bf16).
// Phase B: ST = h1pi @ WF2pi (MFMA from LDS) -> STb (bf16, true order).
// ---------------------------------------------------------------------------
__global__ __launch_bounds__(256, 2)
void agg_gemm2(const int* __restrict__ nidx, const unsigned char* __restrict__ Pf,
               const ushort* __restrict__ Qb, const ushort* __restrict__ WF2,
               ushort* __restrict__ STb) {
    __shared__ char hs[128 * 256];  // 32KB: 128 rows x 128 bf16, swizzled
    const int t = threadIdx.x;
    const int node0 = blockIdx.x * 128;
    const int sl = t & 7;    // 16B fp8-slice of a row (16 elems)
    const int ng = t >> 3;   // node slot 0..31

    const float inv = 1.0f / 16.0f;
    #pragma unroll 1
    for (int it = 0; it < 4; ++it) {
        const int r = ng + it * 32;          // local row 0..127
        int node = node0 + r;
        if (node > NN - 1) node = NN - 1;
        const int2 myn = *(const int2*)(nidx + (size_t)node * DEG + sl * 2);
        const ushort* qp = Qb + (size_t)node * HID + sl * 16;
        const s16x8 q0 = *(const s16x8*)qp;
        const s16x8 q1 = *(const s16x8*)(qp + 8);

        uint4 vv[16];
        #pragma unroll
        for (int d = 0; d < 16; ++d) {
            const uint id = (uint)__shfl((d & 1) ? myn.y : myn.x, d >> 1, 8);
            vv[d] = *(const uint4*)(Pf + (size_t)id * HID + sl * 16);
        }
        __builtin_amdgcn_sched_barrier(0);   // all 16 gathers in flight first

        float s[16];
        #pragma unroll
        for (int j = 0; j < 16; ++j) s[j] = 0.f;
        #pragma unroll
        for (int d = 0; d < 16; ++d) {
            const uint wd[4] = {vv[d].x, vv[d].y, vv[d].z, vv[d].w};
            #pragma unroll
            for (int q = 0; q < 4; ++q) {
                const auto plo = __builtin_amdgcn_cvt_pk_f32_fp8(wd[q], false);
                const auto phi = __builtin_amdgcn_cvt_pk_f32_fp8(wd[q], true);
                s[q * 4 + 0] += plo[0]; s[q * 4 + 1] += plo[1];
                s[q * 4 + 2] += phi[0]; s[q * 4 + 3] += phi[1];
            }
        }

        float h[16];
        #pragma unroll
        for (int j = 0; j < 8; ++j) {
            h[j]     = fmaxf(fmaf(s[j],     inv, bf2f((ushort)q0[j])), 0.f);
            h[j + 8] = fmaxf(fmaf(s[j + 8], inv, bf2f((ushort)q1[j])), 0.f);
        }
        uint4 u0, u1;
        u0.x = cvtpk(h[0], h[1]);   u0.y = cvtpk(h[2], h[3]);
        u0.z = cvtpk(h[4], h[5]);   u0.w = cvtpk(h[6], h[7]);
        u1.x = cvtpk(h[8], h[9]);   u1.y = cvtpk(h[10], h[11]);
        u1.z = cvtpk(h[12], h[13]); u1.w = cvtpk(h[14], h[15]);
        *(uint4*)(hs + swz16(r, sl * 32)) = u0;
        *(uint4*)(hs + swz16(r, sl * 32 + 16)) = u1;
    }
    __syncthreads();

    // Phase B: 4 waves; wave w -> local rows w*32 .. w*32+31 (1 frag)
    const int lane = t & 63;
    const int w = t >> 6;
    const int rl = w * 32;

    f32x16 acc = {0,0,0,0,0,0,0,0,0,0,0,0,0,0,0,0};
    #pragma unroll
    for (int kk = 0; kk < 8; ++kk) {
        const int kb = kk * 32 + (lane >> 5) * 16;
        const s16x8 a = *(const s16x8*)(hs + swz16(rl + (lane & 31), kb));
        const s16x8 b = *(const s16x8*)(WF2 + (size_t)(kk * 64 + lane) * 8);
        acc = __builtin_amdgcn_mfma_f32_32x32x16_bf16(a, b, acc, 0, 0, 0);
    }

    const int col = lane & 31;
    const int crow4 = 4 * (lane >> 5);
    #pragma unroll
    for (int g = 0; g < 16; g += 2) {
        const uint pk = cvtpk(acc[g], acc[g + 1]);
        const int row = node0 + rl + (g & 3) + 8 * (g >> 2) + crow4;
        if (row < NN)     STb[(size_t)row * 32 + col] = (ushort)pk;
        if (row + 1 < NN) STb[(size_t)(row + 1) * 32 + col] = (ushort)(pk >> 16);
    }
}

// ---------------------------------------------------------------------------
// Final: out[b][j] = S[node_b][j] + (1/16)*sum_d T[nbr(node_b,d)][j]
// ---------------------------------------------------------------------------
__global__ __launch_bounds__(256)
void final_out(const int* __restrict__ nodes, const int* __restrict__ nidx,
               const ushort* __restrict__ STb, float* __restrict__ out) {
    const int g = blockIdx.x * 256 + threadIdx.x;
    if (g >= NB * NC / 2) return;
    const int b = g >> 3;
    const int jp = g & 7;
    const int node = nodes[b];
    const uint sv = *(const uint*)(STb + (size_t)node * 32 + jp * 2);
    const int* nb = nidx + (size_t)node * DEG;
    float a0 = 0.f, a1 = 0.f;
    #pragma unroll
    for (int d = 0; d < DEG; ++d) {
        const uint v = *(const uint*)(STb + (size_t)nb[d] * 32 + 16 + jp * 2);
        a0 += bf2f((ushort)v);
        a1 += bf2f((ushort)(v >> 16));
    }
    float2 o;
    o.x = fmaf(a0, 1.0f / 16.0f, bf2f((ushort)sv));
    o.y = fmaf(a1, 1.0f / 16.0f, bf2f((ushort)(sv >> 16)));
    *(float2*)(out + (size_t)b * 16 + jp * 2) = o;
}

extern "C" void kernel_launch(void* const* d_in, const int* in_sizes, int n_in,
                              void* d_out, int out_size, void* d_ws, size_t ws_size,
                              hipStream_t stream) {
    const int* nodes = (const int*)d_in[0];
    const int* nidx  = (const int*)d_in[1];
    const float* X   = (const float*)d_in[2];
    const float* W1  = (const float*)d_in[3];
    const float* W2  = (const float*)d_in[4];
    float* out = (float*)d_out;

    // ws: Qb bf16 25.6MB | Pf fp8 12.8MB | STb bf16 6.4MB | WFh 64KB | WF2 8KB
    ushort* Qb = (ushort*)d_ws;
    unsigned char* Pf = (unsigned char*)(Qb + (size_t)NN * HID);
    ushort* STb = (ushort*)(Pf + (size_t)NN * HID);
    ushort* WFh = STb + (size_t)NN * 32;
    ushort* WF2 = WFh + 64 * 64 * 8;

    wf_prep<<<18, 256, 0, stream>>>(W1, W2, WFh, WF2);
    gemm1<<<1563, 256, 0, stream>>>(X, WFh, Qb, Pf);
    agg_gemm2<<<782, 256, 0, stream>>>(nidx, Pf, Qb, WF2, STb);
    final_out<<<313, 256, 0, stream>>>(nodes, nidx, STb, out);
}

// Round 15
// 75.808 us; speedup vs baseline: 1.0055x; 1.0055x over previous
//
#include <hip/hip_runtime.h>
#include <hip/hip_bf16.h>

#define NN 100000
#define DEG 16
#define NF 128
#define HID 128
#define NC 16
#define NB 10000

#define AS1 __attribute__((address_space(1)))
#define AS3 __attribute__((address_space(3)))

typedef float f32x16 __attribute__((ext_vector_type(16)));
typedef short s16x8 __attribute__((ext_vector_type(8)));

__device__ __forceinline__ ushort f2bf(float f) {   // RNE (prep kernel only)
    unsigned u = __builtin_bit_cast(unsigned, f);
    return (ushort)((u + 0x7FFFu + ((u >> 16) & 1u)) >> 16);
}
__device__ __forceinline__ float bf2f(ushort h) {
    return __builtin_bit_cast(float, (unsigned)h << 16);
}
// HW packed fp32->bf16 RNE: dst = {lo: cvt(a), hi: cvt(b)}
__device__ __forceinline__ uint cvtpk(float a, float b) {
    uint r;
    asm("v_cvt_pk_bf16_f32 %0, %1, %2" : "=v"(r) : "v"(a), "v"(b));
    return r;
}
__device__ __forceinline__ s16x8 pack8(float4 a, float4 b) {
    uint4 u;
    u.x = cvtpk(a.x, a.y);
    u.y = cvtpk(a.z, a.w);
    u.z = cvtpk(b.x, b.y);
    u.w = cvtpk(b.z, b.w);
    return __builtin_bit_cast(s16x8, u);
}
// XOR swizzle within a 256B LDS row: 16 slots of 16B (T2, conflict-free b128)
__device__ __forceinline__ int swz16(int row, int bo) {
    return row * 256 + (bo ^ ((row & 15) << 4));
}
// XOR swizzle for the 512B fp32 A-rows in gemm1 (32 slots of 16B)
__device__ __forceinline__ uint swzA(uint row, uint bo) {
    return bo ^ ((row & 31u) << 4);
}
// pi: storage position p -> true feature index j (within 128)
__device__ __forceinline__ int pi_feat(int p) {
    const int n = p >> 5, h = (p >> 4) & 1, g = p & 15;
    return 32 * n + 4 * h + (g & 3) + 8 * (g >> 2);
}

// ---------------------------------------------------------------------------
// Prep: W1 -> bf16 MFMA A-fragments WFh; W2 -> WF2 with pi-permuted k.
// WFh frag (c,kk): lane l holds Wb[c*32+(l&31)][kk*16+(l>>5)*8 .. +8]
//   Wb[j][k] = j<128 ? W1[j][k] : W1[j-128][128+k]
// WF2 frag (kk):   lane l, elem i holds W2b[(l&31)][pi(kk*16+(l>>5)*8+i)]
// ---------------------------------------------------------------------------
__global__ __launch_bounds__(256)
void wf_prep(const float* __restrict__ W1, const float* __restrict__ W2,
             ushort* __restrict__ WFh, ushort* __restrict__ WF2) {
    const int t = blockIdx.x * 256 + threadIdx.x;
    if (t >= 72 * 64) return;
    const int frag = t >> 6;
    const int lane = t & 63;
    const int k0 = (frag & 7) * 16 + (lane >> 5) * 8;

    if (frag < 64) {
        const int vcol = (frag >> 3) * 32 + (lane & 31);
        const float* src = (vcol < 128) ? W1 + (size_t)vcol * 256
                                        : W1 + (size_t)(vcol - 128) * 256 + 128;
        ushort hh[8];
        #pragma unroll
        for (int j = 0; j < 8; ++j) hh[j] = f2bf(src[k0 + j]);
        *(uint4*)(WFh + (size_t)t * 8) = *(const uint4*)hh;
    } else {
        const int vcol = lane & 31;
        const float* src = (vcol < 16) ? W2 + (size_t)vcol * 256
                                       : W2 + (size_t)(vcol - 16) * 256 + 128;
        ushort hh[8];
        #pragma unroll
        for (int j = 0; j < 8; ++j) hh[j] = f2bf(src[pi_feat(k0 + j)]);
        *(uint4*)(WF2 + (size_t)((frag - 64) * 64 + lane) * 8) = *(const uint4*)hh;
    }
}

// ---------------------------------------------------------------------------
// GEMM1 (LDS-staged A via global_load_lds): 256 threads, 64 nodes x 256 feats.
// Stage: contiguous 32KB X tile -> LDS, source pre-swizzled (rule #21) so the
// compute-phase ds_read_b128 (lane=node, 512B row stride) is conflict-free.
// Compute: 4 waves, wm=w&1 (32-node frag), wn=w>>1 (feature half);
// swapped-operand MFMA -> lane owns one node, pi-contiguous 16B stores.
// Out: feats 0..127 -> Qb (bf16), 128..255 -> Pf (fp8 e4m3), pi-ordered.
// ---------------------------------------------------------------------------
__global__ __launch_bounds__(256, 3)
void gemm1(const float* __restrict__ X, const ushort* __restrict__ WFh,
           ushort* __restrict__ Qb, unsigned char* __restrict__ Pf) {
    __shared__ char As[64 * 512];   // 32KB: 64 rows x 128 fp32, XOR-swizzled
    const int t = threadIdx.x;
    const int lane = t & 63;
    const int w = t >> 6;          // 0..3
    const int row0 = blockIdx.x * 64;

    // ---- stage: 32 chunks of 1KB; wave w takes chunks w, w+4, ... (8 issues)
    #pragma unroll
    for (int j = 0; j < 8; ++j) {
        const uint chunk = (uint)(j * 4 + w);
        const uint o = chunk * 1024u + (uint)lane * 16u;  // LDS byte this lane fills
        const uint rrow = o >> 9;                          // local row 0..63
        const uint bo = o & 511u;
        int grow = row0 + (int)rrow;
        if (grow > NN - 1) grow = NN - 1;
        const char* src = (const char*)X + (size_t)grow * 512 + swzA(rrow, bo);
        __builtin_amdgcn_global_load_lds((const AS1 void*)src,
                                         (AS3 void*)(As + chunk * 1024), 16, 0, 0);
    }
    __syncthreads();

    const int wm = w & 1;          // node frag
    const int wn = w >> 1;         // feature half
    const uint arow = (uint)(wm * 32 + (lane & 31));
    const char* abase = As + arow * 512;

    f32x16 acc[4];
    #pragma unroll
    for (int n = 0; n < 4; ++n)
        acc[n] = (f32x16){0,0,0,0,0,0,0,0,0,0,0,0,0,0,0,0};

    #pragma unroll
    for (int kk = 0; kk < 8; ++kk) {
        const uint bo = (uint)(kk * 64 + (lane >> 5) * 32);
        const float4 fa = *(const float4*)(abase + swzA(arow, bo));
        const float4 fb = *(const float4*)(abase + swzA(arow, bo + 16));
        const s16x8 a = pack8(fa, fb);
        #pragma unroll
        for (int n = 0; n < 4; ++n) {
            const int cf = wn * 4 + n;
            const s16x8 b = *(const s16x8*)(WFh + (size_t)((cf * 8 + kk) * 64 + lane) * 8);
            // swapped: W as A (row=feature), X as B (col=node)
            acc[n] = __builtin_amdgcn_mfma_f32_32x32x16_bf16(b, a, acc[n], 0, 0, 0);
        }
    }

    // ---- epilogue: lane owns node; 16 contiguous pi-positions per frag
    const int node = row0 + wm * 32 + (lane & 31);
    if (node < NN) {
        const int h16 = (lane >> 5) * 16;
        if (wn == 0) {
            ushort* qp = Qb + (size_t)node * HID + h16;
            #pragma unroll
            for (int n = 0; n < 4; ++n) {
                uint4 u0, u1;
                u0.x = cvtpk(acc[n][0], acc[n][1]);
                u0.y = cvtpk(acc[n][2], acc[n][3]);
                u0.z = cvtpk(acc[n][4], acc[n][5]);
                u0.w = cvtpk(acc[n][6], acc[n][7]);
                u1.x = cvtpk(acc[n][8], acc[n][9]);
                u1.y = cvtpk(acc[n][10], acc[n][11]);
                u1.z = cvtpk(acc[n][12], acc[n][13]);
                u1.w = cvtpk(acc[n][14], acc[n][15]);
                *(uint4*)(qp + n * 32) = u0;
                *(uint4*)(qp + n * 32 + 8) = u1;
            }
        } else {
            unsigned char* pp = Pf + (size_t)node * HID + h16;
            #pragma unroll
            for (int n = 0; n < 4; ++n) {
                uint uu[4];
                #pragma unroll
                for (int q = 0; q < 4; ++q) {
                    int v = __builtin_amdgcn_cvt_pk_fp8_f32(
                        acc[n][4 * q], acc[n][4 * q + 1], 0, false);
                    v = __builtin_amdgcn_cvt_pk_fp8_f32(
                        acc[n][4 * q + 2], acc[n][4 * q + 3], v, true);
                    uu[q] = (uint)v;
                }
                *(uint4*)(pp + n * 32) = *(const uint4*)uu;
            }
        }
    }
}

// ---------------------------------------------------------------------------
// Fused aggregate + GEMM2 (all pi-ordered; elementwise ops order-agnostic).
// Block = 128 nodes, 32KB LDS.
// Phase A: h1[n] = relu(Qb[n] + mean_d Pf[nbr(n,d)]) -> swizzled LDS (bf16).
// Phase B: ST = h1pi @ WF2pi (MFMA from LDS) -> STb (bf16, true order).
// ---------------------------------------------------------------------------
__global__ __launch_bounds__(256, 2)
void agg_gemm2(const int* __restrict__ nidx, const unsigned char* __restrict__ Pf,
               const ushort* __restrict__ Qb, const ushort* __restrict__ WF2,
               ushort* __restrict__ STb) {
    __shared__ char hs[128 * 256];  // 32KB: 128 rows x 128 bf16, swizzled
    const int t = threadIdx.x;
    const int node0 = blockIdx.x * 128;
    const int sl = t & 7;    // 16B fp8-slice of a row (16 elems)
    const int ng = t >> 3;   // node slot 0..31

    const float inv = 1.0f / 16.0f;
    #pragma unroll 1
    for (int it = 0; it < 4; ++it) {
        const int r = ng + it * 32;          // local row 0..127
        int node = node0 + r;
        if (node > NN - 1) node = NN - 1;
        const int2 myn = *(const int2*)(nidx + (size_t)node * DEG + sl * 2);
        const ushort* qp = Qb + (size_t)node * HID + sl * 16;
        const s16x8 q0 = *(const s16x8*)qp;
        const s16x8 q1 = *(const s16x8*)(qp + 8);

        uint4 vv[16];
        #pragma unroll
        for (int d = 0; d < 16; ++d) {
            const uint id = (uint)__shfl((d & 1) ? myn.y : myn.x, d >> 1, 8);
            vv[d] = *(const uint4*)(Pf + (size_t)id * HID + sl * 16);
        }
        __builtin_amdgcn_sched_barrier(0);   // all 16 gathers in flight first

        float s[16];
        #pragma unroll
        for (int j = 0; j < 16; ++j) s[j] = 0.f;
        #pragma unroll
        for (int d = 0; d < 16; ++d) {
            const uint wd[4] = {vv[d].x, vv[d].y, vv[d].z, vv[d].w};
            #pragma unroll
            for (int q = 0; q < 4; ++q) {
                const auto plo = __builtin_amdgcn_cvt_pk_f32_fp8(wd[q], false);
                const auto phi = __builtin_amdgcn_cvt_pk_f32_fp8(wd[q], true);
                s[q * 4 + 0] += plo[0]; s[q * 4 + 1] += plo[1];
                s[q * 4 + 2] += phi[0]; s[q * 4 + 3] += phi[1];
            }
        }

        float h[16];
        #pragma unroll
        for (int j = 0; j < 8; ++j) {
            h[j]     = fmaxf(fmaf(s[j],     inv, bf2f((ushort)q0[j])), 0.f);
            h[j + 8] = fmaxf(fmaf(s[j + 8], inv, bf2f((ushort)q1[j])), 0.f);
        }
        uint4 u0, u1;
        u0.x = cvtpk(h[0], h[1]);   u0.y = cvtpk(h[2], h[3]);
        u0.z = cvtpk(h[4], h[5]);   u0.w = cvtpk(h[6], h[7]);
        u1.x = cvtpk(h[8], h[9]);   u1.y = cvtpk(h[10], h[11]);
        u1.z = cvtpk(h[12], h[13]); u1.w = cvtpk(h[14], h[15]);
        *(uint4*)(hs + swz16(r, sl * 32)) = u0;
        *(uint4*)(hs + swz16(r, sl * 32 + 16)) = u1;
    }
    __syncthreads();

    // Phase B: 4 waves; wave w -> local rows w*32 .. w*32+31 (1 frag)
    const int lane = t & 63;
    const int w = t >> 6;
    const int rl = w * 32;

    f32x16 acc = {0,0,0,0,0,0,0,0,0,0,0,0,0,0,0,0};
    #pragma unroll
    for (int kk = 0; kk < 8; ++kk) {
        const int kb = kk * 32 + (lane >> 5) * 16;
        const s16x8 a = *(const s16x8*)(hs + swz16(rl + (lane & 31), kb));
        const s16x8 b = *(const s16x8*)(WF2 + (size_t)(kk * 64 + lane) * 8);
        acc = __builtin_amdgcn_mfma_f32_32x32x16_bf16(a, b, acc, 0, 0, 0);
    }

    const int col = lane & 31;
    const int crow4 = 4 * (lane >> 5);
    #pragma unroll
    for (int g = 0; g < 16; g += 2) {
        const uint pk = cvtpk(acc[g], acc[g + 1]);
        const int row = node0 + rl + (g & 3) + 8 * (g >> 2) + crow4;
        if (row < NN)     STb[(size_t)row * 32 + col] = (ushort)pk;
        if (row + 1 < NN) STb[(size_t)(row + 1) * 32 + col] = (ushort)(pk >> 16);
    }
}

// ---------------------------------------------------------------------------
// Final: out[b][j] = S[node_b][j] + (1/16)*sum_d T[nbr(node_b,d)][j]
// ---------------------------------------------------------------------------
__global__ __launch_bounds__(256)
void final_out(const int* __restrict__ nodes, const int* __restrict__ nidx,
               const ushort* __restrict__ STb, float* __restrict__ out) {
    const int g = blockIdx.x * 256 + threadIdx.x;
    if (g >= NB * NC / 2) return;
    const int b = g >> 3;
    const int jp = g & 7;
    const int node = nodes[b];
    const uint sv = *(const uint*)(STb + (size_t)node * 32 + jp * 2);
    const int* nb = nidx + (size_t)node * DEG;
    float a0 = 0.f, a1 = 0.f;
    #pragma unroll
    for (int d = 0; d < DEG; ++d) {
        const uint v = *(const uint*)(STb + (size_t)nb[d] * 32 + 16 + jp * 2);
        a0 += bf2f((ushort)v);
        a1 += bf2f((ushort)(v >> 16));
    }
    float2 o;
    o.x = fmaf(a0, 1.0f / 16.0f, bf2f((ushort)sv));
    o.y = fmaf(a1, 1.0f / 16.0f, bf2f((ushort)(sv >> 16)));
    *(float2*)(out + (size_t)b * 16 + jp * 2) = o;
}

extern "C" void kernel_launch(void* const* d_in, const int* in_sizes, int n_in,
                              void* d_out, int out_size, void* d_ws, size_t ws_size,
                              hipStream_t stream) {
    const int* nodes = (const int*)d_in[0];
    const int* nidx  = (const int*)d_in[1];
    const float* X   = (const float*)d_in[2];
    const float* W1  = (const float*)d_in[3];
    const float* W2  = (const float*)d_in[4];
    float* out = (float*)d_out;

    // ws: Qb bf16 25.6MB | Pf fp8 12.8MB | STb bf16 6.4MB | WFh 64KB | WF2 8KB
    ushort* Qb = (ushort*)d_ws;
    unsigned char* Pf = (unsigned char*)(Qb + (size_t)NN * HID);
    ushort* STb = (ushort*)(Pf + (size_t)NN * HID);
    ushort* WFh = STb + (size_t)NN * 32;
    ushort* WF2 = WFh + 64 * 64 * 8;

    wf_prep<<<18, 256, 0, stream>>>(W1, W2, WFh, WF2);
    gemm1<<<1563, 256, 0, stream>>>(X, WFh, Qb, Pf);
    agg_gemm2<<<782, 256, 0, stream>>>(nidx, Pf, Qb, WF2, STb);
    final_out<<<313, 256, 0, stream>>>(nodes, nidx, STb, out);
}

// Round 16
// 75.577 us; speedup vs baseline: 1.0086x; 1.0031x over previous
//
#include <hip/hip_runtime.h>
#include <hip/hip_bf16.h>

#define NN 100000
#define DEG 16
#define NF 128
#define HID 128
#define NC 16
#define NB 10000

#define AS1 __attribute__((address_space(1)))
#define AS3 __attribute__((address_space(3)))

typedef float f32x16 __attribute__((ext_vector_type(16)));
typedef short s16x8 __attribute__((ext_vector_type(8)));

__device__ __forceinline__ ushort f2bf(float f) {   // RNE (prep kernel only)
    unsigned u = __builtin_bit_cast(unsigned, f);
    return (ushort)((u + 0x7FFFu + ((u >> 16) & 1u)) >> 16);
}
__device__ __forceinline__ float bf2f(ushort h) {
    return __builtin_bit_cast(float, (unsigned)h << 16);
}
// HW packed fp32->bf16 RNE: dst = {lo: cvt(a), hi: cvt(b)}
__device__ __forceinline__ uint cvtpk(float a, float b) {
    uint r;
    asm("v_cvt_pk_bf16_f32 %0, %1, %2" : "=v"(r) : "v"(a), "v"(b));
    return r;
}
__device__ __forceinline__ s16x8 pack8(float4 a, float4 b) {
    uint4 u;
    u.x = cvtpk(a.x, a.y);
    u.y = cvtpk(a.z, a.w);
    u.z = cvtpk(b.x, b.y);
    u.w = cvtpk(b.z, b.w);
    return __builtin_bit_cast(s16x8, u);
}
// XOR swizzle within a 256B LDS row: 16 slots of 16B (T2, conflict-free b128)
__device__ __forceinline__ int swz16(int row, int bo) {
    return row * 256 + (bo ^ ((row & 15) << 4));
}
// XOR swizzle for the 512B fp32 A-rows in gemm1 (32 slots of 16B)
__device__ __forceinline__ uint swzA(uint row, uint bo) {
    return bo ^ ((row & 31u) << 4);
}
// pi: storage position p -> true feature index j (within 128)
__device__ __forceinline__ int pi_feat(int p) {
    const int n = p >> 5, h = (p >> 4) & 1, g = p & 15;
    return 32 * n + 4 * h + (g & 3) + 8 * (g >> 2);
}

// ---------------------------------------------------------------------------
// Prep: W1 -> bf16 MFMA A-fragments WFh; W2 -> WF2 with pi-permuted k.
// WFh frag (c,kk): lane l holds Wb[c*32+(l&31)][kk*16+(l>>5)*8 .. +8]
//   Wb[j][k] = j<128 ? W1[j][k] : W1[j-128][128+k]
// WF2 frag (kk):   lane l, elem i holds W2b[(l&31)][pi(kk*16+(l>>5)*8+i)]
// ---------------------------------------------------------------------------
__global__ __launch_bounds__(256)
void wf_prep(const float* __restrict__ W1, const float* __restrict__ W2,
             ushort* __restrict__ WFh, ushort* __restrict__ WF2) {
    const int t = blockIdx.x * 256 + threadIdx.x;
    if (t >= 72 * 64) return;
    const int frag = t >> 6;
    const int lane = t & 63;
    const int k0 = (frag & 7) * 16 + (lane >> 5) * 8;

    if (frag < 64) {
        const int vcol = (frag >> 3) * 32 + (lane & 31);
        const float* src = (vcol < 128) ? W1 + (size_t)vcol * 256
                                        : W1 + (size_t)(vcol - 128) * 256 + 128;
        ushort hh[8];
        #pragma unroll
        for (int j = 0; j < 8; ++j) hh[j] = f2bf(src[k0 + j]);
        *(uint4*)(WFh + (size_t)t * 8) = *(const uint4*)hh;
    } else {
        const int vcol = lane & 31;
        const float* src = (vcol < 16) ? W2 + (size_t)vcol * 256
                                       : W2 + (size_t)(vcol - 16) * 256 + 128;
        ushort hh[8];
        #pragma unroll
        for (int j = 0; j < 8; ++j) hh[j] = f2bf(src[pi_feat(k0 + j)]);
        *(uint4*)(WF2 + (size_t)((frag - 64) * 64 + lane) * 8) = *(const uint4*)hh;
    }
}

// ---------------------------------------------------------------------------
// GEMM1 (LDS-staged A via global_load_lds): 256 threads, 64 nodes x 256 feats.
// __launch_bounds__(256,4): 4 blocks/CU (128KB LDS of 160; ~112 unified regs
// fits 4 waves/SIMD) -> +33% in-flight bytes vs (256,3). Latency-bound test.
// ---------------------------------------------------------------------------
__global__ __launch_bounds__(256, 4)
void gemm1(const float* __restrict__ X, const ushort* __restrict__ WFh,
           ushort* __restrict__ Qb, unsigned char* __restrict__ Pf) {
    __shared__ char As[64 * 512];   // 32KB: 64 rows x 128 fp32, XOR-swizzled
    const int t = threadIdx.x;
    const int lane = t & 63;
    const int w = t >> 6;          // 0..3
    const int row0 = blockIdx.x * 64;

    // ---- stage: 32 chunks of 1KB; wave w takes chunks w, w+4, ... (8 issues)
    #pragma unroll
    for (int j = 0; j < 8; ++j) {
        const uint chunk = (uint)(j * 4 + w);
        const uint o = chunk * 1024u + (uint)lane * 16u;  // LDS byte this lane fills
        const uint rrow = o >> 9;                          // local row 0..63
        const uint bo = o & 511u;
        int grow = row0 + (int)rrow;
        if (grow > NN - 1) grow = NN - 1;
        const char* src = (const char*)X + (size_t)grow * 512 + swzA(rrow, bo);
        __builtin_amdgcn_global_load_lds((const AS1 void*)src,
                                         (AS3 void*)(As + chunk * 1024), 16, 0, 0);
    }
    __syncthreads();

    const int wm = w & 1;          // node frag
    const int wn = w >> 1;         // feature half
    const uint arow = (uint)(wm * 32 + (lane & 31));
    const char* abase = As + arow * 512;

    f32x16 acc[4];
    #pragma unroll
    for (int n = 0; n < 4; ++n)
        acc[n] = (f32x16){0,0,0,0,0,0,0,0,0,0,0,0,0,0,0,0};

    #pragma unroll
    for (int kk = 0; kk < 8; ++kk) {
        const uint bo = (uint)(kk * 64 + (lane >> 5) * 32);
        const float4 fa = *(const float4*)(abase + swzA(arow, bo));
        const float4 fb = *(const float4*)(abase + swzA(arow, bo + 16));
        const s16x8 a = pack8(fa, fb);
        #pragma unroll
        for (int n = 0; n < 4; ++n) {
            const int cf = wn * 4 + n;
            const s16x8 b = *(const s16x8*)(WFh + (size_t)((cf * 8 + kk) * 64 + lane) * 8);
            // swapped: W as A (row=feature), X as B (col=node)
            acc[n] = __builtin_amdgcn_mfma_f32_32x32x16_bf16(b, a, acc[n], 0, 0, 0);
        }
    }

    // ---- epilogue: lane owns node; 16 contiguous pi-positions per frag
    const int node = row0 + wm * 32 + (lane & 31);
    if (node < NN) {
        const int h16 = (lane >> 5) * 16;
        if (wn == 0) {
            ushort* qp = Qb + (size_t)node * HID + h16;
            #pragma unroll
            for (int n = 0; n < 4; ++n) {
                uint4 u0, u1;
                u0.x = cvtpk(acc[n][0], acc[n][1]);
                u0.y = cvtpk(acc[n][2], acc[n][3]);
                u0.z = cvtpk(acc[n][4], acc[n][5]);
                u0.w = cvtpk(acc[n][6], acc[n][7]);
                u1.x = cvtpk(acc[n][8], acc[n][9]);
                u1.y = cvtpk(acc[n][10], acc[n][11]);
                u1.z = cvtpk(acc[n][12], acc[n][13]);
                u1.w = cvtpk(acc[n][14], acc[n][15]);
                *(uint4*)(qp + n * 32) = u0;
                *(uint4*)(qp + n * 32 + 8) = u1;
            }
        } else {
            unsigned char* pp = Pf + (size_t)node * HID + h16;
            #pragma unroll
            for (int n = 0; n < 4; ++n) {
                uint uu[4];
                #pragma unroll
                for (int q = 0; q < 4; ++q) {
                    int v = __builtin_amdgcn_cvt_pk_fp8_f32(
                        acc[n][4 * q], acc[n][4 * q + 1], 0, false);
                    v = __builtin_amdgcn_cvt_pk_fp8_f32(
                        acc[n][4 * q + 2], acc[n][4 * q + 3], v, true);
                    uu[q] = (uint)v;
                }
                *(uint4*)(pp + n * 32) = *(const uint4*)uu;
            }
        }
    }
}

// ---------------------------------------------------------------------------
// Fused aggregate + GEMM2 (all pi-ordered; elementwise ops order-agnostic).
// Block = 128 nodes, 32KB LDS. __launch_bounds__(256,3): 3 blocks/CU (96KB
// LDS; ~110 regs fits 3 waves/SIMD — no VGPR squeeze, unlike r5's (256,4)).
// ---------------------------------------------------------------------------
__global__ __launch_bounds__(256, 3)
void agg_gemm2(const int* __restrict__ nidx, const unsigned char* __restrict__ Pf,
               const ushort* __restrict__ Qb, const ushort* __restrict__ WF2,
               ushort* __restrict__ STb) {
    __shared__ char hs[128 * 256];  // 32KB: 128 rows x 128 bf16, swizzled
    const int t = threadIdx.x;
    const int node0 = blockIdx.x * 128;
    const int sl = t & 7;    // 16B fp8-slice of a row (16 elems)
    const int ng = t >> 3;   // node slot 0..31

    const float inv = 1.0f / 16.0f;
    #pragma unroll 1
    for (int it = 0; it < 4; ++it) {
        const int r = ng + it * 32;          // local row 0..127
        int node = node0 + r;
        if (node > NN - 1) node = NN - 1;
        const int2 myn = *(const int2*)(nidx + (size_t)node * DEG + sl * 2);
        const ushort* qp = Qb + (size_t)node * HID + sl * 16;
        const s16x8 q0 = *(const s16x8*)qp;
        const s16x8 q1 = *(const s16x8*)(qp + 8);

        uint4 vv[16];
        #pragma unroll
        for (int d = 0; d < 16; ++d) {
            const uint id = (uint)__shfl((d & 1) ? myn.y : myn.x, d >> 1, 8);
            vv[d] = *(const uint4*)(Pf + (size_t)id * HID + sl * 16);
        }
        __builtin_amdgcn_sched_barrier(0);   // all 16 gathers in flight first

        float s[16];
        #pragma unroll
        for (int j = 0; j < 16; ++j) s[j] = 0.f;
        #pragma unroll
        for (int d = 0; d < 16; ++d) {
            const uint wd[4] = {vv[d].x, vv[d].y, vv[d].z, vv[d].w};
            #pragma unroll
            for (int q = 0; q < 4; ++q) {
                const auto plo = __builtin_amdgcn_cvt_pk_f32_fp8(wd[q], false);
                const auto phi = __builtin_amdgcn_cvt_pk_f32_fp8(wd[q], true);
                s[q * 4 + 0] += plo[0]; s[q * 4 + 1] += plo[1];
                s[q * 4 + 2] += phi[0]; s[q * 4 + 3] += phi[1];
            }
        }

        float h[16];
        #pragma unroll
        for (int j = 0; j < 8; ++j) {
            h[j]     = fmaxf(fmaf(s[j],     inv, bf2f((ushort)q0[j])), 0.f);
            h[j + 8] = fmaxf(fmaf(s[j + 8], inv, bf2f((ushort)q1[j])), 0.f);
        }
        uint4 u0, u1;
        u0.x = cvtpk(h[0], h[1]);   u0.y = cvtpk(h[2], h[3]);
        u0.z = cvtpk(h[4], h[5]);   u0.w = cvtpk(h[6], h[7]);
        u1.x = cvtpk(h[8], h[9]);   u1.y = cvtpk(h[10], h[11]);
        u1.z = cvtpk(h[12], h[13]); u1.w = cvtpk(h[14], h[15]);
        *(uint4*)(hs + swz16(r, sl * 32)) = u0;
        *(uint4*)(hs + swz16(r, sl * 32 + 16)) = u1;
    }
    __syncthreads();

    // Phase B: 4 waves; wave w -> local rows w*32 .. w*32+31 (1 frag)
    const int lane = t & 63;
    const int w = t >> 6;
    const int rl = w * 32;

    f32x16 acc = {0,0,0,0,0,0,0,0,0,0,0,0,0,0,0,0};
    #pragma unroll
    for (int kk = 0; kk < 8; ++kk) {
        const int kb = kk * 32 + (lane >> 5) * 16;
        const s16x8 a = *(const s16x8*)(hs + swz16(rl + (lane & 31), kb));
        const s16x8 b = *(const s16x8*)(WF2 + (size_t)(kk * 64 + lane) * 8);
        acc = __builtin_amdgcn_mfma_f32_32x32x16_bf16(a, b, acc, 0, 0, 0);
    }

    const int col = lane & 31;
    const int crow4 = 4 * (lane >> 5);
    #pragma unroll
    for (int g = 0; g < 16; g += 2) {
        const uint pk = cvtpk(acc[g], acc[g + 1]);
        const int row = node0 + rl + (g & 3) + 8 * (g >> 2) + crow4;
        if (row < NN)     STb[(size_t)row * 32 + col] = (ushort)pk;
        if (row + 1 < NN) STb[(size_t)(row + 1) * 32 + col] = (ushort)(pk >> 16);
    }
}

// ---------------------------------------------------------------------------
// Final: out[b][j] = S[node_b][j] + (1/16)*sum_d T[nbr(node_b,d)][j]
// ---------------------------------------------------------------------------
__global__ __launch_bounds__(256)
void final_out(const int* __restrict__ nodes, const int* __restrict__ nidx,
               const ushort* __restrict__ STb, float* __restrict__ out) {
    const int g = blockIdx.x * 256 + threadIdx.x;
    if (g >= NB * NC / 2) return;
    const int b = g >> 3;
    const int jp = g & 7;
    const int node = nodes[b];
    const uint sv = *(const uint*)(STb + (size_t)node * 32 + jp * 2);
    const int* nb = nidx + (size_t)node * DEG;
    float a0 = 0.f, a1 = 0.f;
    #pragma unroll
    for (int d = 0; d < DEG; ++d) {
        const uint v = *(const uint*)(STb + (size_t)nb[d] * 32 + 16 + jp * 2);
        a0 += bf2f((ushort)v);
        a1 += bf2f((ushort)(v >> 16));
    }
    float2 o;
    o.x = fmaf(a0, 1.0f / 16.0f, bf2f((ushort)sv));
    o.y = fmaf(a1, 1.0f / 16.0f, bf2f((ushort)(sv >> 16)));
    *(float2*)(out + (size_t)b * 16 + jp * 2) = o;
}

extern "C" void kernel_launch(void* const* d_in, const int* in_sizes, int n_in,
                              void* d_out, int out_size, void* d_ws, size_t ws_size,
                              hipStream_t stream) {
    const int* nodes = (const int*)d_in[0];
    const int* nidx  = (const int*)d_in[1];
    const float* X   = (const float*)d_in[2];
    const float* W1  = (const float*)d_in[3];
    const float* W2  = (const float*)d_in[4];
    float* out = (float*)d_out;

    // ws: Qb bf16 25.6MB | Pf fp8 12.8MB | STb bf16 6.4MB | WFh 64KB | WF2 8KB
    ushort* Qb = (ushort*)d_ws;
    unsigned char* Pf = (unsigned char*)(Qb + (size_t)NN * HID);
    ushort* STb = (ushort*)(Pf + (size_t)NN * HID);
    ushort* WFh = STb + (size_t)NN * 32;
    ushort* WF2 = WFh + 64 * 64 * 8;

    wf_prep<<<18, 256, 0, stream>>>(W1, W2, WFh, WF2);
    gemm1<<<1563, 256, 0, stream>>>(X, WFh, Qb, Pf);
    agg_gemm2<<<782, 256, 0, stream>>>(nidx, Pf, Qb, WF2, STb);
    final_out<<<313, 256, 0, stream>>>(nodes, nidx, STb, out);
}

// Round 17
// 72.584 us; speedup vs baseline: 1.0502x; 1.0412x over previous
//
#include <hip/hip_runtime.h>
#include <hip/hip_bf16.h>

#define NN 100000
#define DEG 16
#define NF 128
#define HID 128
#define NC 16
#define NB 10000

#define AS1 __attribute__((address_space(1)))
#define AS3 __attribute__((address_space(3)))

typedef float f32x16 __attribute__((ext_vector_type(16)));
typedef short s16x8 __attribute__((ext_vector_type(8)));

__device__ __forceinline__ ushort f2bf(float f) {   // RNE (prep kernel only)
    unsigned u = __builtin_bit_cast(unsigned, f);
    return (ushort)((u + 0x7FFFu + ((u >> 16) & 1u)) >> 16);
}
__device__ __forceinline__ float bf2f(ushort h) {
    return __builtin_bit_cast(float, (unsigned)h << 16);
}
// HW packed fp32->bf16 RNE: dst = {lo: cvt(a), hi: cvt(b)}
__device__ __forceinline__ uint cvtpk(float a, float b) {
    uint r;
    asm("v_cvt_pk_bf16_f32 %0, %1, %2" : "=v"(r) : "v"(a), "v"(b));
    return r;
}
__device__ __forceinline__ s16x8 pack8(float4 a, float4 b) {
    uint4 u;
    u.x = cvtpk(a.x, a.y);
    u.y = cvtpk(a.z, a.w);
    u.z = cvtpk(b.x, b.y);
    u.w = cvtpk(b.z, b.w);
    return __builtin_bit_cast(s16x8, u);
}
// XOR swizzle within a 256B LDS row: 16 slots of 16B (T2, conflict-free b128)
__device__ __forceinline__ int swz16(int row, int bo) {
    return row * 256 + (bo ^ ((row & 15) << 4));
}
// XOR swizzle for the 512B fp32 A-rows in gemm1 (32 slots of 16B)
__device__ __forceinline__ uint swzA(uint row, uint bo) {
    return bo ^ ((row & 31u) << 4);
}
// pi: storage position p -> true feature index j (within 128)
__device__ __forceinline__ int pi_feat(int p) {
    const int n = p >> 5, h = (p >> 4) & 1, g = p & 15;
    return 32 * n + 4 * h + (g & 3) + 8 * (g >> 2);
}

// ---------------------------------------------------------------------------
// Prep: W1 -> bf16 MFMA A-fragments WFh; W2 -> WF2 with pi-permuted k.
// WFh frag (c,kk): lane l holds Wb[c*32+(l&31)][kk*16+(l>>5)*8 .. +8]
//   Wb[j][k] = j<128 ? W1[j][k] : W1[j-128][128+k]
// WF2 frag (kk):   lane l, elem i holds W2b[(l&31)][pi(kk*16+(l>>5)*8+i)]
// ---------------------------------------------------------------------------
__global__ __launch_bounds__(256)
void wf_prep(const float* __restrict__ W1, const float* __restrict__ W2,
             ushort* __restrict__ WFh, ushort* __restrict__ WF2) {
    const int t = blockIdx.x * 256 + threadIdx.x;
    if (t >= 72 * 64) return;
    const int frag = t >> 6;
    const int lane = t & 63;
    const int k0 = (frag & 7) * 16 + (lane >> 5) * 8;

    if (frag < 64) {
        const int vcol = (frag >> 3) * 32 + (lane & 31);
        const float* src = (vcol < 128) ? W1 + (size_t)vcol * 256
                                        : W1 + (size_t)(vcol - 128) * 256 + 128;
        ushort hh[8];
        #pragma unroll
        for (int j = 0; j < 8; ++j) hh[j] = f2bf(src[k0 + j]);
        *(uint4*)(WFh + (size_t)t * 8) = *(const uint4*)hh;
    } else {
        const int vcol = lane & 31;
        const float* src = (vcol < 16) ? W2 + (size_t)vcol * 256
                                       : W2 + (size_t)(vcol - 16) * 256 + 128;
        ushort hh[8];
        #pragma unroll
        for (int j = 0; j < 8; ++j) hh[j] = f2bf(src[pi_feat(k0 + j)]);
        *(uint4*)(WF2 + (size_t)((frag - 64) * 64 + lane) * 8) = *(const uint4*)hh;
    }
}

// ---------------------------------------------------------------------------
// GEMM1 (T3 minimum 2-phase pipeline): 3 tiles of 64 nodes per block,
// double-buffered 64KB LDS, sync via __syncthreads() ONLY.
//   stage(buf0,t0); sync; { stage(buf^1,t+1); compute(buf,t); sync; }
// Compute+stores of tile t cover the flight time of tile t+1's loads.
// Compute/epilogue identical to the passing r16 kernel.
// ---------------------------------------------------------------------------
__global__ __launch_bounds__(256, 2)
void gemm1(const float* __restrict__ X, const ushort* __restrict__ WFh,
           ushort* __restrict__ Qb, unsigned char* __restrict__ Pf) {
    __shared__ char As[2][32768];   // 2 x 32KB: 64 rows x 128 fp32, XOR-swizzled
    const int t = threadIdx.x;
    const int lane = t & 63;
    const int w = t >> 6;          // 0..3
    const int tileBase = blockIdx.x * 3;

    // ---- prologue: stage tile 0 -> As[0]
    {
        const int row0 = tileBase * 64;
        #pragma unroll
        for (int j = 0; j < 8; ++j) {
            const uint chunk = (uint)(j * 4 + w);
            const uint o = chunk * 1024u + (uint)lane * 16u;
            const uint rrow = o >> 9;
            const uint bo = o & 511u;
            int grow = row0 + (int)rrow;
            if (grow > NN - 1) grow = NN - 1;
            const char* src = (const char*)X + (size_t)grow * 512 + swzA(rrow, bo);
            __builtin_amdgcn_global_load_lds((const AS1 void*)src,
                                             (AS3 void*)(As[0] + chunk * 1024), 16, 0, 0);
        }
    }
    __syncthreads();

    const int wm = w & 1;          // node frag
    const int wn = w >> 1;         // feature half
    const uint arow = (uint)(wm * 32 + (lane & 31));

    #pragma unroll
    for (int tt = 0; tt < 3; ++tt) {
        const int cur = tt & 1;
        // ---- issue next tile's loads into the other buffer (async)
        if (tt < 2) {
            const int row0n = (tileBase + tt + 1) * 64;
            #pragma unroll
            for (int j = 0; j < 8; ++j) {
                const uint chunk = (uint)(j * 4 + w);
                const uint o = chunk * 1024u + (uint)lane * 16u;
                const uint rrow = o >> 9;
                const uint bo = o & 511u;
                int grow = row0n + (int)rrow;
                if (grow > NN - 1) grow = NN - 1;
                const char* src = (const char*)X + (size_t)grow * 512 + swzA(rrow, bo);
                __builtin_amdgcn_global_load_lds((const AS1 void*)src,
                                                 (AS3 void*)(As[cur ^ 1] + chunk * 1024),
                                                 16, 0, 0);
            }
        }
        __builtin_amdgcn_sched_barrier(0);   // pin: issue prefetch before compute

        // ---- compute current tile (identical to r16)
        const int row0 = (tileBase + tt) * 64;
        const char* abase = As[cur] + arow * 512;

        f32x16 acc[4];
        #pragma unroll
        for (int n = 0; n < 4; ++n)
            acc[n] = (f32x16){0,0,0,0,0,0,0,0,0,0,0,0,0,0,0,0};

        #pragma unroll
        for (int kk = 0; kk < 8; ++kk) {
            const uint bo = (uint)(kk * 64 + (lane >> 5) * 32);
            const float4 fa = *(const float4*)(abase + swzA(arow, bo));
            const float4 fb = *(const float4*)(abase + swzA(arow, bo + 16));
            const s16x8 a = pack8(fa, fb);
            #pragma unroll
            for (int n = 0; n < 4; ++n) {
                const int cf = wn * 4 + n;
                const s16x8 b = *(const s16x8*)(WFh + (size_t)((cf * 8 + kk) * 64 + lane) * 8);
                // swapped: W as A (row=feature), X as B (col=node)
                acc[n] = __builtin_amdgcn_mfma_f32_32x32x16_bf16(b, a, acc[n], 0, 0, 0);
            }
        }

        // ---- epilogue: lane owns node; 16 contiguous pi-positions per frag
        const int node = row0 + wm * 32 + (lane & 31);
        if (node < NN) {
            const int h16 = (lane >> 5) * 16;
            if (wn == 0) {
                ushort* qp = Qb + (size_t)node * HID + h16;
                #pragma unroll
                for (int n = 0; n < 4; ++n) {
                    uint4 u0, u1;
                    u0.x = cvtpk(acc[n][0], acc[n][1]);
                    u0.y = cvtpk(acc[n][2], acc[n][3]);
                    u0.z = cvtpk(acc[n][4], acc[n][5]);
                    u0.w = cvtpk(acc[n][6], acc[n][7]);
                    u1.x = cvtpk(acc[n][8], acc[n][9]);
                    u1.y = cvtpk(acc[n][10], acc[n][11]);
                    u1.z = cvtpk(acc[n][12], acc[n][13]);
                    u1.w = cvtpk(acc[n][14], acc[n][15]);
                    *(uint4*)(qp + n * 32) = u0;
                    *(uint4*)(qp + n * 32 + 8) = u1;
                }
            } else {
                unsigned char* pp = Pf + (size_t)node * HID + h16;
                #pragma unroll
                for (int n = 0; n < 4; ++n) {
                    uint uu[4];
                    #pragma unroll
                    for (int q = 0; q < 4; ++q) {
                        int v = __builtin_amdgcn_cvt_pk_fp8_f32(
                            acc[n][4 * q], acc[n][4 * q + 1], 0, false);
                        v = __builtin_amdgcn_cvt_pk_fp8_f32(
                            acc[n][4 * q + 2], acc[n][4 * q + 3], v, true);
                        uu[q] = (uint)v;
                    }
                    *(uint4*)(pp + n * 32) = *(const uint4*)uu;
                }
            }
        }
        __syncthreads();   // next tile's loads landed; everyone done with As[cur]
    }
}

// ---------------------------------------------------------------------------
// Fused aggregate + GEMM2 (all pi-ordered; elementwise ops order-agnostic).
// Block = 128 nodes, 32KB LDS. (256,3): 3 blocks/CU.
// Phase A: h1[n] = relu(Qb[n] + mean_d Pf[nbr(n,d)]) -> swizzled LDS (bf16).
// Phase B: ST = h1pi @ WF2pi (MFMA from LDS) -> STb (bf16, true order).
// ---------------------------------------------------------------------------
__global__ __launch_bounds__(256, 3)
void agg_gemm2(const int* __restrict__ nidx, const unsigned char* __restrict__ Pf,
               const ushort* __restrict__ Qb, const ushort* __restrict__ WF2,
               ushort* __restrict__ STb) {
    __shared__ char hs[128 * 256];  // 32KB: 128 rows x 128 bf16, swizzled
    const int t = threadIdx.x;
    const int node0 = blockIdx.x * 128;
    const int sl = t & 7;    // 16B fp8-slice of a row (16 elems)
    const int ng = t >> 3;   // node slot 0..31

    const float inv = 1.0f / 16.0f;
    #pragma unroll 1
    for (int it = 0; it < 4; ++it) {
        const int r = ng + it * 32;          // local row 0..127
        int node = node0 + r;
        if (node > NN - 1) node = NN - 1;
        const int2 myn = *(const int2*)(nidx + (size_t)node * DEG + sl * 2);
        const ushort* qp = Qb + (size_t)node * HID + sl * 16;
        const s16x8 q0 = *(const s16x8*)qp;
        const s16x8 q1 = *(const s16x8*)(qp + 8);

        uint4 vv[16];
        #pragma unroll
        for (int d = 0; d < 16; ++d) {
            const uint id = (uint)__shfl((d & 1) ? myn.y : myn.x, d >> 1, 8);
            vv[d] = *(const uint4*)(Pf + (size_t)id * HID + sl * 16);
        }
        __builtin_amdgcn_sched_barrier(0);   // all 16 gathers in flight first

        float s[16];
        #pragma unroll
        for (int j = 0; j < 16; ++j) s[j] = 0.f;
        #pragma unroll
        for (int d = 0; d < 16; ++d) {
            const uint wd[4] = {vv[d].x, vv[d].y, vv[d].z, vv[d].w};
            #pragma unroll
            for (int q = 0; q < 4; ++q) {
                const auto plo = __builtin_amdgcn_cvt_pk_f32_fp8(wd[q], false);
                const auto phi = __builtin_amdgcn_cvt_pk_f32_fp8(wd[q], true);
                s[q * 4 + 0] += plo[0]; s[q * 4 + 1] += plo[1];
                s[q * 4 + 2] += phi[0]; s[q * 4 + 3] += phi[1];
            }
        }

        float h[16];
        #pragma unroll
        for (int j = 0; j < 8; ++j) {
            h[j]     = fmaxf(fmaf(s[j],     inv, bf2f((ushort)q0[j])), 0.f);
            h[j + 8] = fmaxf(fmaf(s[j + 8], inv, bf2f((ushort)q1[j])), 0.f);
        }
        uint4 u0, u1;
        u0.x = cvtpk(h[0], h[1]);   u0.y = cvtpk(h[2], h[3]);
        u0.z = cvtpk(h[4], h[5]);   u0.w = cvtpk(h[6], h[7]);
        u1.x = cvtpk(h[8], h[9]);   u1.y = cvtpk(h[10], h[11]);
        u1.z = cvtpk(h[12], h[13]); u1.w = cvtpk(h[14], h[15]);
        *(uint4*)(hs + swz16(r, sl * 32)) = u0;
        *(uint4*)(hs + swz16(r, sl * 32 + 16)) = u1;
    }
    __syncthreads();

    // Phase B: 4 waves; wave w -> local rows w*32 .. w*32+31 (1 frag)
    const int lane = t & 63;
    const int w = t >> 6;
    const int rl = w * 32;

    f32x16 acc = {0,0,0,0,0,0,0,0,0,0,0,0,0,0,0,0};
    #pragma unroll
    for (int kk = 0; kk < 8; ++kk) {
        const int kb = kk * 32 + (lane >> 5) * 16;
        const s16x8 a = *(const s16x8*)(hs + swz16(rl + (lane & 31), kb));
        const s16x8 b = *(const s16x8*)(WF2 + (size_t)(kk * 64 + lane) * 8);
        acc = __builtin_amdgcn_mfma_f32_32x32x16_bf16(a, b, acc, 0, 0, 0);
    }

    const int col = lane & 31;
    const int crow4 = 4 * (lane >> 5);
    #pragma unroll
    for (int g = 0; g < 16; g += 2) {
        const uint pk = cvtpk(acc[g], acc[g + 1]);
        const int row = node0 + rl + (g & 3) + 8 * (g >> 2) + crow4;
        if (row < NN)     STb[(size_t)row * 32 + col] = (ushort)pk;
        if (row + 1 < NN) STb[(size_t)(row + 1) * 32 + col] = (ushort)(pk >> 16);
    }
}

// ---------------------------------------------------------------------------
// Final: out[b][j] = S[node_b][j] + (1/16)*sum_d T[nbr(node_b,d)][j]
// ---------------------------------------------------------------------------
__global__ __launch_bounds__(256)
void final_out(const int* __restrict__ nodes, const int* __restrict__ nidx,
               const ushort* __restrict__ STb, float* __restrict__ out) {
    const int g = blockIdx.x * 256 + threadIdx.x;
    if (g >= NB * NC / 2) return;
    const int b = g >> 3;
    const int jp = g & 7;
    const int node = nodes[b];
    const uint sv = *(const uint*)(STb + (size_t)node * 32 + jp * 2);
    const int* nb = nidx + (size_t)node * DEG;
    float a0 = 0.f, a1 = 0.f;
    #pragma unroll
    for (int d = 0; d < DEG; ++d) {
        const uint v = *(const uint*)(STb + (size_t)nb[d] * 32 + 16 + jp * 2);
        a0 += bf2f((ushort)v);
        a1 += bf2f((ushort)(v >> 16));
    }
    float2 o;
    o.x = fmaf(a0, 1.0f / 16.0f, bf2f((ushort)sv));
    o.y = fmaf(a1, 1.0f / 16.0f, bf2f((ushort)(sv >> 16)));
    *(float2*)(out + (size_t)b * 16 + jp * 2) = o;
}

extern "C" void kernel_launch(void* const* d_in, const int* in_sizes, int n_in,
                              void* d_out, int out_size, void* d_ws, size_t ws_size,
                              hipStream_t stream) {
    const int* nodes = (const int*)d_in[0];
    const int* nidx  = (const int*)d_in[1];
    const float* X   = (const float*)d_in[2];
    const float* W1  = (const float*)d_in[3];
    const float* W2  = (const float*)d_in[4];
    float* out = (float*)d_out;

    // ws: Qb bf16 25.6MB | Pf fp8 12.8MB | STb bf16 6.4MB | WFh 64KB | WF2 8KB
    ushort* Qb = (ushort*)d_ws;
    unsigned char* Pf = (unsigned char*)(Qb + (size_t)NN * HID);
    ushort* STb = (ushort*)(Pf + (size_t)NN * HID);
    ushort* WFh = STb + (size_t)NN * 32;
    ushort* WF2 = WFh + 64 * 64 * 8;

    wf_prep<<<18, 256, 0, stream>>>(W1, W2, WFh, WF2);
    gemm1<<<521, 256, 0, stream>>>(X, WFh, Qb, Pf);   // 521 blocks x 3 tiles = 1563
    agg_gemm2<<<782, 256, 0, stream>>>(nidx, Pf, Qb, WF2, STb);
    final_out<<<313, 256, 0, stream>>>(nodes, nidx, STb, out);
}

// Round 18
// 69.222 us; speedup vs baseline: 1.1012x; 1.0486x over previous
//
#include <hip/hip_runtime.h>
#include <hip/hip_bf16.h>

#define NN 100000
#define DEG 16
#define NF 128
#define HID 128
#define NC 16
#define NB 10000

#define AS1 __attribute__((address_space(1)))
#define AS3 __attribute__((address_space(3)))

typedef float f32x16 __attribute__((ext_vector_type(16)));
typedef short s16x8 __attribute__((ext_vector_type(8)));

__device__ __forceinline__ ushort f2bf(float f) {   // RNE (prep kernel only)
    unsigned u = __builtin_bit_cast(unsigned, f);
    return (ushort)((u + 0x7FFFu + ((u >> 16) & 1u)) >> 16);
}
__device__ __forceinline__ float bf2f(ushort h) {
    return __builtin_bit_cast(float, (unsigned)h << 16);
}
// HW packed fp32->bf16 RNE: dst = {lo: cvt(a), hi: cvt(b)}
__device__ __forceinline__ uint cvtpk(float a, float b) {
    uint r;
    asm("v_cvt_pk_bf16_f32 %0, %1, %2" : "=v"(r) : "v"(a), "v"(b));
    return r;
}
__device__ __forceinline__ s16x8 pack8(float4 a, float4 b) {
    uint4 u;
    u.x = cvtpk(a.x, a.y);
    u.y = cvtpk(a.z, a.w);
    u.z = cvtpk(b.x, b.y);
    u.w = cvtpk(b.z, b.w);
    return __builtin_bit_cast(s16x8, u);
}
// XOR swizzle within a 256B LDS row: 16 slots of 16B (T2, conflict-free b128)
__device__ __forceinline__ int swz16(int row, int bo) {
    return row * 256 + (bo ^ ((row & 15) << 4));
}
// XOR swizzle for the 512B fp32 A-rows in gemm1 (32 slots of 16B)
__device__ __forceinline__ uint swzA(uint row, uint bo) {
    return bo ^ ((row & 31u) << 4);
}
// pi: storage position p -> true feature index j (within 128)
__device__ __forceinline__ int pi_feat(int p) {
    const int n = p >> 5, h = (p >> 4) & 1, g = p & 15;
    return 32 * n + 4 * h + (g & 3) + 8 * (g >> 2);
}

// ---------------------------------------------------------------------------
// Prep: W1 -> bf16 MFMA A-fragments WFh; W2 -> WF2 with pi-permuted k.
// WFh frag (c,kk): lane l holds Wb[c*32+(l&31)][kk*16+(l>>5)*8 .. +8]
//   Wb[j][k] = j<128 ? W1[j][k] : W1[j-128][128+k]
// WF2 frag (kk):   lane l, elem i holds W2b[(l&31)][pi(kk*16+(l>>5)*8+i)]
// ---------------------------------------------------------------------------
__global__ __launch_bounds__(256)
void wf_prep(const float* __restrict__ W1, const float* __restrict__ W2,
             ushort* __restrict__ WFh, ushort* __restrict__ WF2) {
    const int t = blockIdx.x * 256 + threadIdx.x;
    if (t >= 72 * 64) return;
    const int frag = t >> 6;
    const int lane = t & 63;
    const int k0 = (frag & 7) * 16 + (lane >> 5) * 8;

    if (frag < 64) {
        const int vcol = (frag >> 3) * 32 + (lane & 31);
        const float* src = (vcol < 128) ? W1 + (size_t)vcol * 256
                                        : W1 + (size_t)(vcol - 128) * 256 + 128;
        ushort hh[8];
        #pragma unroll
        for (int j = 0; j < 8; ++j) hh[j] = f2bf(src[k0 + j]);
        *(uint4*)(WFh + (size_t)t * 8) = *(const uint4*)hh;
    } else {
        const int vcol = lane & 31;
        const float* src = (vcol < 16) ? W2 + (size_t)vcol * 256
                                       : W2 + (size_t)(vcol - 16) * 256 + 128;
        ushort hh[8];
        #pragma unroll
        for (int j = 0; j < 8; ++j) hh[j] = f2bf(src[pi_feat(k0 + j)]);
        *(uint4*)(WF2 + (size_t)((frag - 64) * 64 + lane) * 8) = *(const uint4*)hh;
    }
}

// ---------------------------------------------------------------------------
// GEMM1 (2-phase pipeline + register-resident B): 3 tiles of 64 nodes per
// block, double-buffered 64KB LDS. B-fragments (32 x s16x8 = 128 VGPR) are
// loaded ONCE per block before the prologue stage (flight time hides under
// stage+sync) and reused across all 3 tiles -> per-tile compute touches no
// global memory: pure ds_read_b128 -> cvt_pk -> MFMA.
// ---------------------------------------------------------------------------
__global__ __launch_bounds__(256, 2)
void gemm1(const float* __restrict__ X, const ushort* __restrict__ WFh,
           ushort* __restrict__ Qb, unsigned char* __restrict__ Pf) {
    __shared__ char As[2][32768];   // 2 x 32KB: 64 rows x 128 fp32, XOR-swizzled
    const int t = threadIdx.x;
    const int lane = t & 63;
    const int w = t >> 6;          // 0..3
    const int wm = w & 1;          // node frag
    const int wn = w >> 1;         // feature half
    const int tileBase = blockIdx.x * 3;

    // ---- preload B fragments for this wave's column-half (reused 3 tiles);
    //      issued first so the L2 latency hides under the stage + sync.
    s16x8 Bf[32];
    #pragma unroll
    for (int kk = 0; kk < 8; ++kk) {
        #pragma unroll
        for (int n = 0; n < 4; ++n) {
            const int cf = wn * 4 + n;
            Bf[kk * 4 + n] = *(const s16x8*)(WFh + (size_t)((cf * 8 + kk) * 64 + lane) * 8);
        }
    }

    // ---- prologue: stage tile 0 -> As[0]
    {
        const int row0 = tileBase * 64;
        #pragma unroll
        for (int j = 0; j < 8; ++j) {
            const uint chunk = (uint)(j * 4 + w);
            const uint o = chunk * 1024u + (uint)lane * 16u;
            const uint rrow = o >> 9;
            const uint bo = o & 511u;
            int grow = row0 + (int)rrow;
            if (grow > NN - 1) grow = NN - 1;
            const char* src = (const char*)X + (size_t)grow * 512 + swzA(rrow, bo);
            __builtin_amdgcn_global_load_lds((const AS1 void*)src,
                                             (AS3 void*)(As[0] + chunk * 1024), 16, 0, 0);
        }
    }
    __syncthreads();

    const uint arow = (uint)(wm * 32 + (lane & 31));

    #pragma unroll
    for (int tt = 0; tt < 3; ++tt) {
        const int cur = tt & 1;
        // ---- issue next tile's loads into the other buffer (async)
        if (tt < 2) {
            const int row0n = (tileBase + tt + 1) * 64;
            #pragma unroll
            for (int j = 0; j < 8; ++j) {
                const uint chunk = (uint)(j * 4 + w);
                const uint o = chunk * 1024u + (uint)lane * 16u;
                const uint rrow = o >> 9;
                const uint bo = o & 511u;
                int grow = row0n + (int)rrow;
                if (grow > NN - 1) grow = NN - 1;
                const char* src = (const char*)X + (size_t)grow * 512 + swzA(rrow, bo);
                __builtin_amdgcn_global_load_lds((const AS1 void*)src,
                                                 (AS3 void*)(As[cur ^ 1] + chunk * 1024),
                                                 16, 0, 0);
            }
        }
        __builtin_amdgcn_sched_barrier(0);   // pin: issue prefetch before compute

        // ---- compute current tile (LDS + registers only)
        const int row0 = (tileBase + tt) * 64;
        const char* abase = As[cur] + arow * 512;

        f32x16 acc[4];
        #pragma unroll
        for (int n = 0; n < 4; ++n)
            acc[n] = (f32x16){0,0,0,0,0,0,0,0,0,0,0,0,0,0,0,0};

        #pragma unroll
        for (int kk = 0; kk < 8; ++kk) {
            const uint bo = (uint)(kk * 64 + (lane >> 5) * 32);
            const float4 fa = *(const float4*)(abase + swzA(arow, bo));
            const float4 fb = *(const float4*)(abase + swzA(arow, bo + 16));
            const s16x8 a = pack8(fa, fb);
            #pragma unroll
            for (int n = 0; n < 4; ++n) {
                // swapped: W as A (row=feature), X as B (col=node)
                acc[n] = __builtin_amdgcn_mfma_f32_32x32x16_bf16(Bf[kk * 4 + n], a, acc[n], 0, 0, 0);
            }
        }

        // ---- epilogue: lane owns node; 16 contiguous pi-positions per frag
        const int node = row0 + wm * 32 + (lane & 31);
        if (node < NN) {
            const int h16 = (lane >> 5) * 16;
            if (wn == 0) {
                ushort* qp = Qb + (size_t)node * HID + h16;
                #pragma unroll
                for (int n = 0; n < 4; ++n) {
                    uint4 u0, u1;
                    u0.x = cvtpk(acc[n][0], acc[n][1]);
                    u0.y = cvtpk(acc[n][2], acc[n][3]);
                    u0.z = cvtpk(acc[n][4], acc[n][5]);
                    u0.w = cvtpk(acc[n][6], acc[n][7]);
                    u1.x = cvtpk(acc[n][8], acc[n][9]);
                    u1.y = cvtpk(acc[n][10], acc[n][11]);
                    u1.z = cvtpk(acc[n][12], acc[n][13]);
                    u1.w = cvtpk(acc[n][14], acc[n][15]);
                    *(uint4*)(qp + n * 32) = u0;
                    *(uint4*)(qp + n * 32 + 8) = u1;
                }
            } else {
                unsigned char* pp = Pf + (size_t)node * HID + h16;
                #pragma unroll
                for (int n = 0; n < 4; ++n) {
                    uint uu[4];
                    #pragma unroll
                    for (int q = 0; q < 4; ++q) {
                        int v = __builtin_amdgcn_cvt_pk_fp8_f32(
                            acc[n][4 * q], acc[n][4 * q + 1], 0, false);
                        v = __builtin_amdgcn_cvt_pk_fp8_f32(
                            acc[n][4 * q + 2], acc[n][4 * q + 3], v, true);
                        uu[q] = (uint)v;
                    }
                    *(uint4*)(pp + n * 32) = *(const uint4*)uu;
                }
            }
        }
        __syncthreads();   // next tile's loads landed; everyone done with As[cur]
    }
}

// ---------------------------------------------------------------------------
// Fused aggregate + GEMM2 (all pi-ordered; elementwise ops order-agnostic).
// Block = 128 nodes, 32KB LDS. (256,3): 3 blocks/CU.
// Phase A: h1[n] = relu(Qb[n] + mean_d Pf[nbr(n,d)]) -> swizzled LDS (bf16).
// Phase B: ST = h1pi @ WF2pi (MFMA from LDS) -> STb (bf16, true order).
// ---------------------------------------------------------------------------
__global__ __launch_bounds__(256, 3)
void agg_gemm2(const int* __restrict__ nidx, const unsigned char* __restrict__ Pf,
               const ushort* __restrict__ Qb, const ushort* __restrict__ WF2,
               ushort* __restrict__ STb) {
    __shared__ char hs[128 * 256];  // 32KB: 128 rows x 128 bf16, swizzled
    const int t = threadIdx.x;
    const int node0 = blockIdx.x * 128;
    const int sl = t & 7;    // 16B fp8-slice of a row (16 elems)
    const int ng = t >> 3;   // node slot 0..31

    const float inv = 1.0f / 16.0f;
    #pragma unroll 1
    for (int it = 0; it < 4; ++it) {
        const int r = ng + it * 32;          // local row 0..127
        int node = node0 + r;
        if (node > NN - 1) node = NN - 1;
        const int2 myn = *(const int2*)(nidx + (size_t)node * DEG + sl * 2);
        const ushort* qp = Qb + (size_t)node * HID + sl * 16;
        const s16x8 q0 = *(const s16x8*)qp;
        const s16x8 q1 = *(const s16x8*)(qp + 8);

        uint4 vv[16];
        #pragma unroll
        for (int d = 0; d < 16; ++d) {
            const uint id = (uint)__shfl((d & 1) ? myn.y : myn.x, d >> 1, 8);
            vv[d] = *(const uint4*)(Pf + (size_t)id * HID + sl * 16);
        }
        __builtin_amdgcn_sched_barrier(0);   // all 16 gathers in flight first

        float s[16];
        #pragma unroll
        for (int j = 0; j < 16; ++j) s[j] = 0.f;
        #pragma unroll
        for (int d = 0; d < 16; ++d) {
            const uint wd[4] = {vv[d].x, vv[d].y, vv[d].z, vv[d].w};
            #pragma unroll
            for (int q = 0; q < 4; ++q) {
                const auto plo = __builtin_amdgcn_cvt_pk_f32_fp8(wd[q], false);
                const auto phi = __builtin_amdgcn_cvt_pk_f32_fp8(wd[q], true);
                s[q * 4 + 0] += plo[0]; s[q * 4 + 1] += plo[1];
                s[q * 4 + 2] += phi[0]; s[q * 4 + 3] += phi[1];
            }
        }

        float h[16];
        #pragma unroll
        for (int j = 0; j < 8; ++j) {
            h[j]     = fmaxf(fmaf(s[j],     inv, bf2f((ushort)q0[j])), 0.f);
            h[j + 8] = fmaxf(fmaf(s[j + 8], inv, bf2f((ushort)q1[j])), 0.f);
        }
        uint4 u0, u1;
        u0.x = cvtpk(h[0], h[1]);   u0.y = cvtpk(h[2], h[3]);
        u0.z = cvtpk(h[4], h[5]);   u0.w = cvtpk(h[6], h[7]);
        u1.x = cvtpk(h[8], h[9]);   u1.y = cvtpk(h[10], h[11]);
        u1.z = cvtpk(h[12], h[13]); u1.w = cvtpk(h[14], h[15]);
        *(uint4*)(hs + swz16(r, sl * 32)) = u0;
        *(uint4*)(hs + swz16(r, sl * 32 + 16)) = u1;
    }
    __syncthreads();

    // Phase B: 4 waves; wave w -> local rows w*32 .. w*32+31 (1 frag)
    const int lane = t & 63;
    const int w = t >> 6;
    const int rl = w * 32;

    f32x16 acc = {0,0,0,0,0,0,0,0,0,0,0,0,0,0,0,0};
    #pragma unroll
    for (int kk = 0; kk < 8; ++kk) {
        const int kb = kk * 32 + (lane >> 5) * 16;
        const s16x8 a = *(const s16x8*)(hs + swz16(rl + (lane & 31), kb));
        const s16x8 b = *(const s16x8*)(WF2 + (size_t)(kk * 64 + lane) * 8);
        acc = __builtin_amdgcn_mfma_f32_32x32x16_bf16(a, b, acc, 0, 0, 0);
    }

    const int col = lane & 31;
    const int crow4 = 4 * (lane >> 5);
    #pragma unroll
    for (int g = 0; g < 16; g += 2) {
        const uint pk = cvtpk(acc[g], acc[g + 1]);
        const int row = node0 + rl + (g & 3) + 8 * (g >> 2) + crow4;
        if (row < NN)     STb[(size_t)row * 32 + col] = (ushort)pk;
        if (row + 1 < NN) STb[(size_t)(row + 1) * 32 + col] = (ushort)(pk >> 16);
    }
}

// ---------------------------------------------------------------------------
// Final: out[b][j] = S[node_b][j] + (1/16)*sum_d T[nbr(node_b,d)][j]
// ---------------------------------------------------------------------------
__global__ __launch_bounds__(256)
void final_out(const int* __restrict__ nodes, const int* __restrict__ nidx,
               const ushort* __restrict__ STb, float* __restrict__ out) {
    const int g = blockIdx.x * 256 + threadIdx.x;
    if (g >= NB * NC / 2) return;
    const int b = g >> 3;
    const int jp = g & 7;
    const int node = nodes[b];
    const uint sv = *(const uint*)(STb + (size_t)node * 32 + jp * 2);
    const int* nb = nidx + (size_t)node * DEG;
    float a0 = 0.f, a1 = 0.f;
    #pragma unroll
    for (int d = 0; d < DEG; ++d) {
        const uint v = *(const uint*)(STb + (size_t)nb[d] * 32 + 16 + jp * 2);
        a0 += bf2f((ushort)v);
        a1 += bf2f((ushort)(v >> 16));
    }
    float2 o;
    o.x = fmaf(a0, 1.0f / 16.0f, bf2f((ushort)sv));
    o.y = fmaf(a1, 1.0f / 16.0f, bf2f((ushort)(sv >> 16)));
    *(float2*)(out + (size_t)b * 16 + jp * 2) = o;
}

extern "C" void kernel_launch(void* const* d_in, const int* in_sizes, int n_in,
                              void* d_out, int out_size, void* d_ws, size_t ws_size,
                              hipStream_t stream) {
    const int* nodes = (const int*)d_in[0];
    const int* nidx  = (const int*)d_in[1];
    const float* X   = (const float*)d_in[2];
    const float* W1  = (const float*)d_in[3];
    const float* W2  = (const float*)d_in[4];
    float* out = (float*)d_out;

    // ws: Qb bf16 25.6MB | Pf fp8 12.8MB | STb bf16 6.4MB | WFh 64KB | WF2 8KB
    ushort* Qb = (ushort*)d_ws;
    unsigned char* Pf = (unsigned char*)(Qb + (size_t)NN * HID);
    ushort* STb = (ushort*)(Pf + (size_t)NN * HID);
    ushort* WFh = STb + (size_t)NN * 32;
    ushort* WF2 = WFh + 64 * 64 * 8;

    wf_prep<<<18, 256, 0, stream>>>(W1, W2, WFh, WF2);
    gemm1<<<521, 256, 0, stream>>>(X, WFh, Qb, Pf);   // 521 blocks x 3 tiles = 1563
    agg_gemm2<<<782, 256, 0, stream>>>(nidx, Pf, Qb, WF2, STb);
    final_out<<<313, 256, 0, stream>>>(nodes, nidx, STb, out);
}

// Round 20
// 64.194 us; speedup vs baseline: 1.1874x; 1.0783x over previous
//
#include <hip/hip_runtime.h>
#include <hip/hip_bf16.h>

#define NN 100000
#define DEG 16
#define NF 128
#define HID 128
#define NC 16
#define NB 10000

#define AS1 __attribute__((address_space(1)))
#define AS3 __attribute__((address_space(3)))

typedef float f32x16 __attribute__((ext_vector_type(16)));
typedef short s16x8 __attribute__((ext_vector_type(8)));

__device__ __forceinline__ ushort f2bf(float f) {   // RNE (prep kernel only)
    unsigned u = __builtin_bit_cast(unsigned, f);
    return (ushort)((u + 0x7FFFu + ((u >> 16) & 1u)) >> 16);
}
__device__ __forceinline__ float bf2f(ushort h) {
    return __builtin_bit_cast(float, (unsigned)h << 16);
}
// HW packed fp32->bf16 RNE: dst = {lo: cvt(a), hi: cvt(b)}
__device__ __forceinline__ uint cvtpk(float a, float b) {
    uint r;
    asm("v_cvt_pk_bf16_f32 %0, %1, %2" : "=v"(r) : "v"(a), "v"(b));
    return r;
}
__device__ __forceinline__ s16x8 pack8(float4 a, float4 b) {
    uint4 u;
    u.x = cvtpk(a.x, a.y);
    u.y = cvtpk(a.z, a.w);
    u.z = cvtpk(b.x, b.y);
    u.w = cvtpk(b.z, b.w);
    return __builtin_bit_cast(s16x8, u);
}
// XOR swizzle within a 256B LDS row: 16 slots of 16B (T2, conflict-free b128)
__device__ __forceinline__ int swz16(int row, int bo) {
    return row * 256 + (bo ^ ((row & 15) << 4));
}
// XOR swizzle for the 512B fp32 A-rows in gemm1 (32 slots of 16B)
__device__ __forceinline__ uint swzA(uint row, uint bo) {
    return bo ^ ((row & 31u) << 4);
}
// pi: storage position p -> true feature index j (within 128)
__device__ __forceinline__ int pi_feat(int p) {
    const int n = p >> 5, h = (p >> 4) & 1, g = p & 15;
    return 32 * n + 4 * h + (g & 3) + 8 * (g >> 2);
}

// ---------------------------------------------------------------------------
// Prep: W1 -> bf16 MFMA A-fragments WFh; W2 -> WF2 with pi-permuted k.
// WFh frag (c,kk): lane l holds Wb[c*32+(l&31)][kk*16+(l>>5)*8 .. +8]
//   Wb[j][k] = j<128 ? W1[j][k] : W1[j-128][128+k]
// WF2 frag (kk):   lane l, elem i holds W2b[(l&31)][pi(kk*16+(l>>5)*8+i)]
// ---------------------------------------------------------------------------
__global__ __launch_bounds__(256)
void wf_prep(const float* __restrict__ W1, const float* __restrict__ W2,
             ushort* __restrict__ WFh, ushort* __restrict__ WF2) {
    const int t = blockIdx.x * 256 + threadIdx.x;
    if (t >= 72 * 64) return;
    const int frag = t >> 6;
    const int lane = t & 63;
    const int k0 = (frag & 7) * 16 + (lane >> 5) * 8;

    if (frag < 64) {
        const int vcol = (frag >> 3) * 32 + (lane & 31);
        const float* src = (vcol < 128) ? W1 + (size_t)vcol * 256
                                        : W1 + (size_t)(vcol - 128) * 256 + 128;
        ushort hh[8];
        #pragma unroll
        for (int j = 0; j < 8; ++j) hh[j] = f2bf(src[k0 + j]);
        *(uint4*)(WFh + (size_t)t * 8) = *(const uint4*)hh;
    } else {
        const int vcol = lane & 31;
        const float* src = (vcol < 16) ? W2 + (size_t)vcol * 256
                                       : W2 + (size_t)(vcol - 16) * 256 + 128;
        ushort hh[8];
        #pragma unroll
        for (int j = 0; j < 8; ++j) hh[j] = f2bf(src[pi_feat(k0 + j)]);
        *(uint4*)(WF2 + (size_t)((frag - 64) * 64 + lane) * 8) = *(const uint4*)hh;
    }
}

// ---------------------------------------------------------------------------
// GEMM1 (2-phase pipeline + register-resident B): 512 blocks, grid-strided
// tiles of 64 nodes (blocks 0..26 take 4 tiles, rest 3; 485*3+27*4 = 1563).
// Double-buffered 64KB LDS. B-fragments (32 x s16x8 = 128 VGPR) loaded once
// per block from WFh (flight hides under prologue stage + sync), reused
// across all tiles -> per-tile compute touches no global memory.
// ---------------------------------------------------------------------------
__global__ __launch_bounds__(256, 2)
void gemm1(const float* __restrict__ X, const ushort* __restrict__ WFh,
           ushort* __restrict__ Qb, unsigned char* __restrict__ Pf) {
    __shared__ char As[2][32768];   // 2 x 32KB: 64 rows x 128 fp32, XOR-swizzled
    const int t = threadIdx.x;
    const int lane = t & 63;
    const int w = t >> 6;          // 0..3
    const int wm = w & 1;          // node frag
    const int wn = w >> 1;         // feature half
    const int bid = blockIdx.x;
    const int nt = (bid < 27) ? 4 : 3;

    // ---- preload B fragments for this wave's column-half (reused all tiles)
    s16x8 Bf[32];
    #pragma unroll
    for (int kk = 0; kk < 8; ++kk) {
        #pragma unroll
        for (int n = 0; n < 4; ++n) {
            const int cf = wn * 4 + n;
            Bf[kk * 4 + n] = *(const s16x8*)(WFh + (size_t)((cf * 8 + kk) * 64 + lane) * 8);
        }
    }

    // ---- prologue: stage tile 0 (= tile index bid) -> As[0]
    {
        const int row0 = bid * 64;
        #pragma unroll
        for (int j = 0; j < 8; ++j) {
            const uint chunk = (uint)(j * 4 + w);
            const uint o = chunk * 1024u + (uint)lane * 16u;
            const uint rrow = o >> 9;
            const uint bo = o & 511u;
            int grow = row0 + (int)rrow;
            if (grow > NN - 1) grow = NN - 1;
            const char* src = (const char*)X + (size_t)grow * 512 + swzA(rrow, bo);
            __builtin_amdgcn_global_load_lds((const AS1 void*)src,
                                             (AS3 void*)(As[0] + chunk * 1024), 16, 0, 0);
        }
    }
    __syncthreads();

    const uint arow = (uint)(wm * 32 + (lane & 31));

    for (int r = 0; r < nt; ++r) {
        const int cur = r & 1;
        // ---- issue next tile's loads into the other buffer (async)
        if (r + 1 < nt) {
            const int row0n = (bid + (r + 1) * 512) * 64;
            #pragma unroll
            for (int j = 0; j < 8; ++j) {
                const uint chunk = (uint)(j * 4 + w);
                const uint o = chunk * 1024u + (uint)lane * 16u;
                const uint rrow = o >> 9;
                const uint bo = o & 511u;
                int grow = row0n + (int)rrow;
                if (grow > NN - 1) grow = NN - 1;
                const char* src = (const char*)X + (size_t)grow * 512 + swzA(rrow, bo);
                __builtin_amdgcn_global_load_lds((const AS1 void*)src,
                                                 (AS3 void*)(As[cur ^ 1] + chunk * 1024),
                                                 16, 0, 0);
            }
        }
        __builtin_amdgcn_sched_barrier(0);   // pin: issue prefetch before compute

        // ---- compute current tile (LDS + registers only)
        const int row0 = (bid + r * 512) * 64;
        const char* abase = As[cur] + arow * 512;

        f32x16 acc[4];
        #pragma unroll
        for (int n = 0; n < 4; ++n)
            acc[n] = (f32x16){0,0,0,0,0,0,0,0,0,0,0,0,0,0,0,0};

        #pragma unroll
        for (int kk = 0; kk < 8; ++kk) {
            const uint bo = (uint)(kk * 64 + (lane >> 5) * 32);
            const float4 fa = *(const float4*)(abase + swzA(arow, bo));
            const float4 fb = *(const float4*)(abase + swzA(arow, bo + 16));
            const s16x8 a = pack8(fa, fb);
            #pragma unroll
            for (int n = 0; n < 4; ++n) {
                // swapped: W as A (row=feature), X as B (col=node)
                acc[n] = __builtin_amdgcn_mfma_f32_32x32x16_bf16(Bf[kk * 4 + n], a, acc[n], 0, 0, 0);
            }
        }

        // ---- epilogue: lane owns node; 16 contiguous pi-positions per frag
        const int node = row0 + wm * 32 + (lane & 31);
        if (node < NN) {
            const int h16 = (lane >> 5) * 16;
            if (wn == 0) {
                ushort* qp = Qb + (size_t)node * HID + h16;
                #pragma unroll
                for (int n = 0; n < 4; ++n) {
                    uint4 u0, u1;
                    u0.x = cvtpk(acc[n][0], acc[n][1]);
                    u0.y = cvtpk(acc[n][2], acc[n][3]);
                    u0.z = cvtpk(acc[n][4], acc[n][5]);
                    u0.w = cvtpk(acc[n][6], acc[n][7]);
                    u1.x = cvtpk(acc[n][8], acc[n][9]);
                    u1.y = cvtpk(acc[n][10], acc[n][11]);
                    u1.z = cvtpk(acc[n][12], acc[n][13]);
                    u1.w = cvtpk(acc[n][14], acc[n][15]);
                    *(uint4*)(qp + n * 32) = u0;
                    *(uint4*)(qp + n * 32 + 8) = u1;
                }
            } else {
                unsigned char* pp = Pf + (size_t)node * HID + h16;
                #pragma unroll
                for (int n = 0; n < 4; ++n) {
                    uint uu[4];
                    #pragma unroll
                    for (int q = 0; q < 4; ++q) {
                        int v = __builtin_amdgcn_cvt_pk_fp8_f32(
                            acc[n][4 * q], acc[n][4 * q + 1], 0, false);
                        v = __builtin_amdgcn_cvt_pk_fp8_f32(
                            acc[n][4 * q + 2], acc[n][4 * q + 3], v, true);
                        uu[q] = (uint)v;
                    }
                    *(uint4*)(pp + n * 32) = *(const uint4*)uu;
                }
            }
        }
        __syncthreads();   // next tile's loads landed; everyone done with As[cur]
    }
}

// ---------------------------------------------------------------------------
// Fused aggregate + GEMM2 (all pi-ordered; elementwise ops order-agnostic).
// Block = 128 nodes, 32KB LDS. (256,3): 3 blocks/CU.
// Phase A: h1[n] = relu(Qb[n] + mean_d Pf[nbr(n,d)]) -> swizzled LDS (bf16).
// Phase B: ST = h1pi @ WF2pi (MFMA from LDS) -> STb (bf16, true order).
// ---------------------------------------------------------------------------
__global__ __launch_bounds__(256, 3)
void agg_gemm2(const int* __restrict__ nidx, const unsigned char* __restrict__ Pf,
               const ushort* __restrict__ Qb, const ushort* __restrict__ WF2,
               ushort* __restrict__ STb) {
    __shared__ char hs[128 * 256];  // 32KB: 128 rows x 128 bf16, swizzled
    const int t = threadIdx.x;
    const int node0 = blockIdx.x * 128;
    const int sl = t & 7;    // 16B fp8-slice of a row (16 elems)
    const int ng = t >> 3;   // node slot 0..31

    const float inv = 1.0f / 16.0f;
    #pragma unroll 1
    for (int it = 0; it < 4; ++it) {
        const int r = ng + it * 32;          // local row 0..127
        int node = node0 + r;
        if (node > NN - 1) node = NN - 1;
        const int2 myn = *(const int2*)(nidx + (size_t)node * DEG + sl * 2);
        const ushort* qp = Qb + (size_t)node * HID + sl * 16;
        const s16x8 q0 = *(const s16x8*)qp;
        const s16x8 q1 = *(const s16x8*)(qp + 8);

        uint4 vv[16];
        #pragma unroll
        for (int d = 0; d < 16; ++d) {
            const uint id = (uint)__shfl((d & 1) ? myn.y : myn.x, d >> 1, 8);
            vv[d] = *(const uint4*)(Pf + (size_t)id * HID + sl * 16);
        }
        __builtin_amdgcn_sched_barrier(0);   // all 16 gathers in flight first

        float s[16];
        #pragma unroll
        for (int j = 0; j < 16; ++j) s[j] = 0.f;
        #pragma unroll
        for (int d = 0; d < 16; ++d) {
            const uint wd[4] = {vv[d].x, vv[d].y, vv[d].z, vv[d].w};
            #pragma unroll
            for (int q = 0; q < 4; ++q) {
                const auto plo = __builtin_amdgcn_cvt_pk_f32_fp8(wd[q], false);
                const auto phi = __builtin_amdgcn_cvt_pk_f32_fp8(wd[q], true);
                s[q * 4 + 0] += plo[0]; s[q * 4 + 1] += plo[1];
                s[q * 4 + 2] += phi[0]; s[q * 4 + 3] += phi[1];
            }
        }

        float h[16];
        #pragma unroll
        for (int j = 0; j < 8; ++j) {
            h[j]     = fmaxf(fmaf(s[j],     inv, bf2f((ushort)q0[j])), 0.f);
            h[j + 8] = fmaxf(fmaf(s[j + 8], inv, bf2f((ushort)q1[j])), 0.f);
        }
        uint4 u0, u1;
        u0.x = cvtpk(h[0], h[1]);   u0.y = cvtpk(h[2], h[3]);
        u0.z = cvtpk(h[4], h[5]);   u0.w = cvtpk(h[6], h[7]);
        u1.x = cvtpk(h[8], h[9]);   u1.y = cvtpk(h[10], h[11]);
        u1.z = cvtpk(h[12], h[13]); u1.w = cvtpk(h[14], h[15]);
        *(uint4*)(hs + swz16(r, sl * 32)) = u0;
        *(uint4*)(hs + swz16(r, sl * 32 + 16)) = u1;
    }
    __syncthreads();

    // Phase B: 4 waves; wave w -> local rows w*32 .. w*32+31 (1 frag)
    const int lane = t & 63;
    const int w = t >> 6;
    const int rl = w * 32;

    f32x16 acc = {0,0,0,0,0,0,0,0,0,0,0,0,0,0,0,0};
    #pragma unroll
    for (int kk = 0; kk < 8; ++kk) {
        const int kb = kk * 32 + (lane >> 5) * 16;
        const s16x8 a = *(const s16x8*)(hs + swz16(rl + (lane & 31), kb));
        const s16x8 b = *(const s16x8*)(WF2 + (size_t)(kk * 64 + lane) * 8);
        acc = __builtin_amdgcn_mfma_f32_32x32x16_bf16(a, b, acc, 0, 0, 0);
    }

    const int col = lane & 31;
    const int crow4 = 4 * (lane >> 5);
    #pragma unroll
    for (int g = 0; g < 16; g += 2) {
        const uint pk = cvtpk(acc[g], acc[g + 1]);
        const int row = node0 + rl + (g & 3) + 8 * (g >> 2) + crow4;
        if (row < NN)     STb[(size_t)row * 32 + col] = (ushort)pk;
        if (row + 1 < NN) STb[(size_t)(row + 1) * 32 + col] = (ushort)(pk >> 16);
    }
}

// ---------------------------------------------------------------------------
// Final: out[b][j] = S[node_b][j] + (1/16)*sum_d T[nbr(node_b,d)][j]
// ---------------------------------------------------------------------------
__global__ __launch_bounds__(256)
void final_out(const int* __restrict__ nodes, const int* __restrict__ nidx,
               const ushort* __restrict__ STb, float* __restrict__ out) {
    const int g = blockIdx.x * 256 + threadIdx.x;
    if (g >= NB * NC / 2) return;
    const int b = g >> 3;
    const int jp = g & 7;
    const int node = nodes[b];
    const uint sv = *(const uint*)(STb + (size_t)node * 32 + jp * 2);
    const int* nb = nidx + (size_t)node * DEG;
    float a0 = 0.f, a1 = 0.f;
    #pragma unroll
    for (int d = 0; d < DEG; ++d) {
        const uint v = *(const uint*)(STb + (size_t)nb[d] * 32 + 16 + jp * 2);
        a0 += bf2f((ushort)v);
        a1 += bf2f((ushort)(v >> 16));
    }
    float2 o;
    o.x = fmaf(a0, 1.0f / 16.0f, bf2f((ushort)sv));
    o.y = fmaf(a1, 1.0f / 16.0f, bf2f((ushort)(sv >> 16)));
    *(float2*)(out + (size_t)b * 16 + jp * 2) = o;
}

extern "C" void kernel_launch(void* const* d_in, const int* in_sizes, int n_in,
                              void* d_out, int out_size, void* d_ws, size_t ws_size,
                              hipStream_t stream) {
    const int* nodes = (const int*)d_in[0];
    const int* nidx  = (const int*)d_in[1];
    const float* X   = (const float*)d_in[2];
    const float* W1  = (const float*)d_in[3];
    const float* W2  = (const float*)d_in[4];
    float* out = (float*)d_out;

    // ws: Qb bf16 25.6MB | Pf fp8 12.8MB | STb bf16 6.4MB | WFh 64KB | WF2 8KB
    ushort* Qb = (ushort*)d_ws;
    unsigned char* Pf = (unsigned char*)(Qb + (size_t)NN * HID);
    ushort* STb = (ushort*)(Pf + (size_t)NN * HID);
    ushort* WFh = STb + (size_t)NN * 32;
    ushort* WF2 = WFh + 64 * 64 * 8;

    wf_prep<<<18, 256, 0, stream>>>(W1, W2, WFh, WF2);
    gemm1<<<512, 256, 0, stream>>>(X, WFh, Qb, Pf);   // grid-strided: 512 blocks, 3-4 tiles
    agg_gemm2<<<782, 256, 0, stream>>>(nidx, Pf, Qb, WF2, STb);
    final_out<<<313, 256, 0, stream>>>(nodes, nidx, STb, out);
}